// Round 1
// baseline (570.670 us; speedup 1.0000x reference)
//
#include <hip/hip_runtime.h>

// ---------------------------------------------------------------------------
// LuminanceAwareMHSA: B=4, C=256, H=W=48 (N=2304), HEADS=8, DH=32, HID=128
// Round 1: correctness-first full pipeline (see header analysis in commit msg).
//   K1  luma + min/max norm + pooled-invL bias (also zeroes hm_sum)
//   K2  conv1 3x3 (1->128) + relu
//   K2b transpose c2_w -> wt[ic][tap][oc] (enables scalar-broadcast weights)
//   K3  conv2 3x3 (128->128) + relu + spatial-mean (atomicAdd into hm_sum)
//   K4  FiLM params (6 small GEMVs)
//   K5  QKV GEMM + FiLM -> bf16 q_t/k_t [B,H,N,32] (SCALE folded into q),
//                          bf16 v [B,256,N]
//   K6  flash attention, mfma_f32_16x16x32_bf16, no-max online softmax
//   K7  output projection (fp32 GEMM, bf16 attn input) -> d_out
// ---------------------------------------------------------------------------

#define NSP 2304
#define WID 48

typedef __attribute__((ext_vector_type(4))) float  fvec4;
typedef __attribute__((ext_vector_type(2))) unsigned int uvec2;
typedef __attribute__((ext_vector_type(8))) short  short8;   // 8 bf16 (4 VGPRs)
typedef __attribute__((ext_vector_type(4))) float  f32x4;    // MFMA C/D

__device__ inline unsigned short f2bf(float f){
  unsigned int u = __builtin_bit_cast(unsigned int, f);
  u += 0x7fffu + ((u >> 16) & 1u);           // RNE
  return (unsigned short)(u >> 16);
}
__device__ inline float bf2f(unsigned short h){
  unsigned int u = ((unsigned int)h) << 16;
  return __builtin_bit_cast(float, u);
}

// LDS swizzle helpers (keep write/read mappings consistent).
// kt: K tile [ml 0..63][d 0..31] bf16, 8-elem blocks xor-swizzled by (ml&3)
__device__ inline int kt_addr(int ml, int d){ return ml*32 + (((d>>3) ^ (ml&3))<<3) + (d&7); }
// vt: V tile [d 0..31][ml 0..63] bf16, 8-elem blocks xor-swizzled by (d&7)
__device__ inline int vt_addr(int d, int ml){ return d*64 + (((ml>>3) ^ (d&7))<<3) + (ml&7); }
// ps: P scratch [n 0..15][m 0..63] f32, 4-elem blocks xor-swizzled by (n&15)
__device__ inline int ps_addr(int n, int m){ return n*64 + ((((m>>2) ^ (n&15)))<<2) + (m&3); }

// ---------------------------------------------------------------------------
// K1: luma -> minmax-normalize; 3x3 zero-pad avg-pool of (1-luma); mean-center
//     and pre-multiply by alpha. Also zero hm_sum for K3's atomics.
__global__ void k1_luma(const float* __restrict__ rgb, const float* __restrict__ alphaP,
                        float* __restrict__ luma_n, float* __restrict__ bias_a,
                        float* __restrict__ hm_sum){
  int b = blockIdx.x, t = threadIdx.x;
  __shared__ float ly[NSP];
  __shared__ float ll[NSP];
  __shared__ float red[256];
  __shared__ float red2[256];
  const float* rp = rgb + b*3*NSP;
  float lmin = 1e30f, lmax = -1e30f;
  for (int i = t; i < NSP; i += 256){
    float y = 0.299f*rp[i] + 0.587f*rp[NSP+i] + 0.114f*rp[2*NSP+i];
    ly[i] = y; lmin = fminf(lmin, y); lmax = fmaxf(lmax, y);
  }
  red[t] = lmin; red2[t] = lmax;
  __syncthreads();
  for (int s = 128; s > 0; s >>= 1){
    if (t < s){ red[t] = fminf(red[t], red[t+s]); red2[t] = fmaxf(red2[t], red2[t+s]); }
    __syncthreads();
  }
  float mn = red[0], mx = red2[0];
  float inv = 1.0f / (mx - mn + 1e-6f);
  for (int i = t; i < NSP; i += 256){
    float v = (ly[i] - mn) * inv;
    ll[i] = v;
    luma_n[b*NSP + i] = v;
  }
  if (t < 128) hm_sum[b*128 + t] = 0.f;
  __syncthreads();
  float pr[9]; float psum = 0.f;
  #pragma unroll
  for (int ii = 0; ii < 9; ++ii){
    int n = t + 256*ii;
    int row = n / WID, col = n - row*WID;
    float s = 0.f;
    #pragma unroll
    for (int dy = -1; dy <= 1; ++dy)
      #pragma unroll
      for (int dx = -1; dx <= 1; ++dx){
        int r2 = row+dy, c2 = col+dx;
        if (r2 >= 0 && r2 < WID && c2 >= 0 && c2 < WID) s += 1.0f - ll[r2*WID + c2];
      }
    pr[ii] = s * (1.f/9.f);
    psum += pr[ii];
  }
  __syncthreads();
  red[t] = psum;
  __syncthreads();
  for (int s = 128; s > 0; s >>= 1){
    if (t < s) red[t] += red[t+s];
    __syncthreads();
  }
  float mean = red[0] * (1.f/(float)NSP);
  float alpha = alphaP[0];
  #pragma unroll
  for (int ii = 0; ii < 9; ++ii){
    int n = t + 256*ii;
    bias_a[b*NSP + n] = alpha * (pr[ii] - mean);
  }
}

// ---------------------------------------------------------------------------
// K2: conv1 3x3, 1 -> 128 channels, relu. grid (9 ntile, 4 ocg, 4 b)
__global__ void k2_conv1(const float* __restrict__ luma_n, const float* __restrict__ c1w,
                         const float* __restrict__ c1b, float* __restrict__ h1){
  int nt = blockIdx.x, ocg = blockIdx.y, b = blockIdx.z, t = threadIdx.x;
  __shared__ float wsm[32*9];
  __shared__ float bsm[32];
  for (int i = t; i < 288; i += 256) wsm[i] = c1w[ocg*288 + i];
  if (t < 32) bsm[t] = c1b[ocg*32 + t];
  __syncthreads();
  int n = nt*256 + t;
  int row = n / WID, col = n - row*WID;
  const float* lp = luma_n + b*NSP;
  float lv[9];
  int k = 0;
  #pragma unroll
  for (int dy = -1; dy <= 1; ++dy)
    #pragma unroll
    for (int dx = -1; dx <= 1; ++dx, ++k){
      int r2 = row+dy, c2 = col+dx;
      lv[k] = (r2 >= 0 && r2 < WID && c2 >= 0 && c2 < WID) ? lp[r2*WID + c2] : 0.f;
    }
  for (int oc = 0; oc < 32; ++oc){
    float a = bsm[oc];
    #pragma unroll
    for (int q = 0; q < 9; ++q) a += wsm[oc*9 + q] * lv[q];
    h1[(b*128 + ocg*32 + oc)*NSP + n] = fmaxf(a, 0.f);
  }
}

// ---------------------------------------------------------------------------
// K2b: wt[((ic*9)+tap)*128 + oc] = c2_w[oc][ic][tap]  (147456 elems)
__global__ void k2b_wt(const float* __restrict__ c2w, float* __restrict__ wt){
  int idx = blockIdx.x*256 + threadIdx.x;
  int oc = idx & 127, rem = idx >> 7;
  int tap = rem % 9, ic = rem / 9;
  wt[idx] = c2w[(oc*128 + ic)*9 + tap];
}

// ---------------------------------------------------------------------------
// K3: conv2 3x3 128->128, relu, spatial mean -> atomicAdd into hm_sum.
// Weights via wave-uniform (scalar) loads from wt; h1 via L1-cached vector
// loads. grid (9 ntile, 8 ocg(16 oc), 4 b). Each thread: 1 position, 16 oc.
__global__ __launch_bounds__(256) void k3_conv2(const float* __restrict__ h1,
                        const float* __restrict__ wt, const float* __restrict__ c2b,
                        float* __restrict__ hm_sum){
  int nt = blockIdx.x, ocg = blockIdx.y, b = blockIdx.z, t = threadIdx.x;
  int n = nt*256 + t;
  int row = n / WID, col = n - row*WID;
  int off[9]; bool valid[9];
  int k = 0;
  #pragma unroll
  for (int dy = -1; dy <= 1; ++dy)
    #pragma unroll
    for (int dx = -1; dx <= 1; ++dx, ++k){
      off[k] = dy*WID + dx;
      int r2 = row+dy, c2 = col+dx;
      valid[k] = (r2 >= 0 && r2 < WID && c2 >= 0 && c2 < WID);
    }
  float acc[16];
  #pragma unroll
  for (int i = 0; i < 16; ++i) acc[i] = c2b[ocg*16 + i];
  const float* hb = h1 + b*128*NSP + n;
  for (int ic = 0; ic < 128; ++ic){
    const float* hrow = hb + ic*NSP;
    #pragma unroll
    for (int tp = 0; tp < 9; ++tp){
      float v = valid[tp] ? hrow[off[tp]] : 0.f;
      const float* wr = wt + (ic*9 + tp)*128 + ocg*16;   // wave-uniform -> s_load
      #pragma unroll
      for (int i = 0; i < 16; ++i) acc[i] += v * wr[i];
    }
  }
  __shared__ float red[4][16];
  int lane = t & 63, wv = t >> 6;
  #pragma unroll
  for (int i = 0; i < 16; ++i){
    float r = fmaxf(acc[i], 0.f);
    #pragma unroll
    for (int o2 = 32; o2 > 0; o2 >>= 1) r += __shfl_xor(r, o2, 64);
    if (lane == 0) red[wv][i] = r;
  }
  __syncthreads();
  if (t < 16){
    float s = red[0][t] + red[1][t] + red[2][t] + red[3][t];
    atomicAdd(&hm_sum[b*128 + ocg*16 + t], s);
  }
}

// ---------------------------------------------------------------------------
// K4: FiLM params. film[(m6*4 + b)*256 + o], m6: 0=gq 1=bqf 2=gk 3=bkf 4=gv 5=bvf
__global__ void k4_film(const float* __restrict__ hm_sum,
  const float* w0, const float* b0, const float* w1, const float* b1,
  const float* w2, const float* b2, const float* w3, const float* b3,
  const float* w4, const float* b4, const float* w5, const float* b5,
  float* __restrict__ film){
  __shared__ float hs[128];
  int bb = blockIdx.x & 3, m6 = blockIdx.x >> 2, t = threadIdx.x;
  if (t < 128) hs[t] = hm_sum[bb*128 + t] * (1.f/(float)NSP);
  __syncthreads();
  const float* wm[6] = {w0,w1,w2,w3,w4,w5};
  const float* bm[6] = {b0,b1,b2,b3,b4,b5};
  const float* w = wm[m6];
  int o = t;
  float a = bm[m6][o];
  for (int h2 = 0; h2 < 128; ++h2) a += hs[h2] * w[o*128 + h2];
  film[blockIdx.x*256 + t] = a;
}

// ---------------------------------------------------------------------------
// K5: q/k/v = FiLM(x @ w^T + b). fp32 tiled GEMM (64o x 64n per block, all 3
// projections share the staged x tile). Emits bf16: q_t,k_t [B,8,N,32]
// (SCALE folded into q), v [B,256,N]. grid (36 nt, 4 ot, 4 b).
__global__ __launch_bounds__(256) void k5_qkv(const float* __restrict__ x,
    const float* __restrict__ wq, const float* __restrict__ wk, const float* __restrict__ wv_,
    const float* __restrict__ bq, const float* __restrict__ bk, const float* __restrict__ bv,
    const float* __restrict__ film,
    unsigned short* __restrict__ q_t, unsigned short* __restrict__ k_t,
    unsigned short* __restrict__ v_b){
  int nt = blockIdx.x, ot = blockIdx.y, b = blockIdx.z, t = threadIdx.x;
  int to = t >> 4, tn = t & 15;
  __shared__ float xs[32][68];
  __shared__ float wsm[3][32][68];
  float acc[3][4][4];
  #pragma unroll
  for (int p = 0; p < 3; ++p)
    #pragma unroll
    for (int i = 0; i < 4; ++i)
      #pragma unroll
      for (int j = 0; j < 4; ++j) acc[p][i][j] = 0.f;
  const float* wmats[3] = {wq, wk, wv_};
  for (int kc = 0; kc < 8; ++kc){
    __syncthreads();
    #pragma unroll
    for (int p2 = 0; p2 < 2; ++p2){
      int idx = t + 256*p2, k = idx >> 4, c4 = idx & 15;
      fvec4 xv = *(const fvec4*)(x + (b*256 + kc*32 + k)*NSP + nt*64 + c4*4);
      *(fvec4*)&xs[k][c4*4] = xv;
    }
    #pragma unroll
    for (int p = 0; p < 3; ++p){
      #pragma unroll
      for (int p2 = 0; p2 < 2; ++p2){
        int idx = t + 256*p2, o = idx >> 3, c4 = idx & 7;
        fvec4 w4 = *(const fvec4*)(wmats[p] + (ot*64 + o)*256 + kc*32 + c4*4);
        wsm[p][c4*4+0][o] = w4[0]; wsm[p][c4*4+1][o] = w4[1];
        wsm[p][c4*4+2][o] = w4[2]; wsm[p][c4*4+3][o] = w4[3];
      }
    }
    __syncthreads();
    for (int k = 0; k < 32; ++k){
      fvec4 xv = *(fvec4*)&xs[k][tn*4];
      #pragma unroll
      for (int p = 0; p < 3; ++p){
        fvec4 w4 = *(fvec4*)&wsm[p][k][to*4];
        #pragma unroll
        for (int i = 0; i < 4; ++i)
          #pragma unroll
          for (int j = 0; j < 4; ++j) acc[p][i][j] += w4[i]*xv[j];
      }
    }
  }
  const float* bvecs[3] = {bq, bk, bv};
  int obase = ot*64 + to*4;
  #pragma unroll
  for (int p = 0; p < 3; ++p){
    float vals[4][4];
    #pragma unroll
    for (int i = 0; i < 4; ++i){
      int o = obase + i;
      float g  = film[(2*p*4 + b)*256 + o];
      float bt = film[((2*p+1)*4 + b)*256 + o];
      float bz = bvecs[p][o];
      #pragma unroll
      for (int j = 0; j < 4; ++j){
        float val = g*(acc[p][i][j] + bz) + bt;
        if (p == 0) val *= 0.17677669529663687f;  // SCALE = DH^-0.5
        vals[i][j] = val;
      }
    }
    if (p < 2){
      unsigned short* dst = (p == 0) ? q_t : k_t;
      int hh = obase >> 5, d0 = obase & 31;
      #pragma unroll
      for (int j = 0; j < 4; ++j){
        int n = nt*64 + tn*4 + j;
        uvec2 u;
        u.x = (unsigned)f2bf(vals[0][j]) | ((unsigned)f2bf(vals[1][j]) << 16);
        u.y = (unsigned)f2bf(vals[2][j]) | ((unsigned)f2bf(vals[3][j]) << 16);
        *(uvec2*)(dst + ((b*8 + hh)*NSP + n)*32 + d0) = u;
      }
    } else {
      int n0 = nt*64 + tn*4;
      #pragma unroll
      for (int i = 0; i < 4; ++i){
        int o = obase + i;
        uvec2 u;
        u.x = (unsigned)f2bf(vals[i][0]) | ((unsigned)f2bf(vals[i][1]) << 16);
        u.y = (unsigned)f2bf(vals[i][2]) | ((unsigned)f2bf(vals[i][3]) << 16);
        *(uvec2*)(v_b + (b*256 + o)*NSP + n0) = u;
      }
    }
  }
}

// ---------------------------------------------------------------------------
// K6: flash attention, mfma_f32_16x16x32_bf16, no-max online softmax.
// Block: 4 waves x 32 queries = 128 queries. m-loop tiles of 64 keys.
// Layouts (verified per guide): A[m=lane&15][k=(lane>>4)*8+j],
// B[k=(lane>>4)*8+j][n=lane&15], D[row=(lane>>4)*4+reg][col=lane&15].
// grid (18 qblk, 8 h, 4 b).
__global__ __launch_bounds__(256) void k6_attn(const unsigned short* __restrict__ q_t,
    const unsigned short* __restrict__ k_t, const unsigned short* __restrict__ v_b,
    const float* __restrict__ bias_a, unsigned short* __restrict__ attn_o){
  int qblk = blockIdx.x, h = blockIdx.y, b = blockIdx.z;
  int t = threadIdx.x, wv = t >> 6, lane = t & 63;
  int lq = lane >> 4, lc = lane & 15;
  __shared__ unsigned short kt[64*32];
  __shared__ unsigned short vt[32*64];
  __shared__ float ps[4][16*64];     // per-wave P scratch (swizzled)
  __shared__ float lbuf[4][2][16];
  int bh = b*8 + h;
  const f32x4 z4 = {0.f, 0.f, 0.f, 0.f};
  short8 aQ[2];
  int nb0 = qblk*128 + wv*32;
  #pragma unroll
  for (int qf = 0; qf < 2; ++qf){
    const unsigned short* qp = q_t + (bh*NSP + nb0 + qf*16 + lc)*32 + lq*8;
    aQ[qf] = *(const short8*)qp;
  }
  f32x4 O[2][2];
  float lpart[2][4];
  #pragma unroll
  for (int qf = 0; qf < 2; ++qf){
    #pragma unroll
    for (int dh = 0; dh < 2; ++dh) O[qf][dh] = z4;
    #pragma unroll
    for (int r = 0; r < 4; ++r) lpart[qf][r] = 0.f;
  }
  const float* brow = bias_a + b*NSP;
  float* myps = ps[wv];

  for (int m0 = 0; m0 < NSP; m0 += 64){
    __syncthreads();
    // stage K tile [64m][32d] (swizzled)
    #pragma unroll
    for (int p2 = 0; p2 < 2; ++p2){
      int ml = (t >> 3) + 32*p2, ch = t & 7;
      uvec2 d2 = *(const uvec2*)(k_t + (bh*NSP + m0 + ml)*32 + ch*4);
      *(uvec2*)&kt[kt_addr(ml, ch*4)] = d2;
    }
    // stage V tile [32d][64m] (swizzled)
    #pragma unroll
    for (int p2 = 0; p2 < 2; ++p2){
      int d = (t >> 4) + 16*p2, c16 = t & 15;
      uvec2 d2 = *(const uvec2*)(v_b + (b*256 + h*32 + d)*NSP + m0 + c16*4);
      *(uvec2*)&vt[vt_addr(d, c16*4)] = d2;
    }
    __syncthreads();
    // V A-fragments (shared by both q-frags)
    short8 aV[2][2];
    #pragma unroll
    for (int dh = 0; dh < 2; ++dh)
      #pragma unroll
      for (int mh = 0; mh < 2; ++mh)
        aV[dh][mh] = *(const short8*)&vt[vt_addr(dh*16 + lc, mh*32 + lq*8)];
    #pragma unroll
    for (int qf = 0; qf < 2; ++qf){
      // S = Q^T K (4 x 16 key-cols)
      f32x4 S[4];
      #pragma unroll
      for (int g = 0; g < 4; ++g){
        short8 bK = *(const short8*)&kt[kt_addr(g*16 + lc, lq*8)];
        S[g] = __builtin_amdgcn_mfma_f32_16x16x32_bf16(aQ[qf], bK, z4, 0, 0, 0);
      }
      // P = exp(S + bias[m]); accumulate row-sum partials; scratch in swizzled LDS
      #pragma unroll
      for (int g = 0; g < 4; ++g){
        float bias = brow[m0 + g*16 + lc];
        #pragma unroll
        for (int r = 0; r < 4; ++r){
          float p = __expf(S[g][r] + bias);
          lpart[qf][r] += p;
          myps[ps_addr(lq*4 + r, g*16 + lc)] = p;
        }
      }
      // PV: O^T[d][n] += V[d][m] * P^T[m][n]
      #pragma unroll
      for (int mh = 0; mh < 2; ++mh){
        fvec4 p0 = *(fvec4*)&myps[ps_addr(lc, mh*32 + lq*8)];
        fvec4 p1 = *(fvec4*)&myps[ps_addr(lc, mh*32 + lq*8 + 4)];
        short8 bP;
        bP[0] = (short)f2bf(p0[0]); bP[1] = (short)f2bf(p0[1]);
        bP[2] = (short)f2bf(p0[2]); bP[3] = (short)f2bf(p0[3]);
        bP[4] = (short)f2bf(p1[0]); bP[5] = (short)f2bf(p1[1]);
        bP[6] = (short)f2bf(p1[2]); bP[7] = (short)f2bf(p1[3]);
        #pragma unroll
        for (int dh = 0; dh < 2; ++dh)
          O[qf][dh] = __builtin_amdgcn_mfma_f32_16x16x32_bf16(aV[dh][mh], bP, O[qf][dh], 0, 0, 0);
      }
    }
  }
  // epilogue: row sums across the 16 lanes of each quad, normalize, store bf16
  #pragma unroll
  for (int qf = 0; qf < 2; ++qf){
    #pragma unroll
    for (int r = 0; r < 4; ++r){
      float lv = lpart[qf][r];
      lv += __shfl_xor(lv, 1, 64);
      lv += __shfl_xor(lv, 2, 64);
      lv += __shfl_xor(lv, 4, 64);
      lv += __shfl_xor(lv, 8, 64);
      if (lc == 0) lbuf[wv][qf][lq*4 + r] = lv;
    }
    __syncthreads();
    float rl = 1.0f / lbuf[wv][qf][lc];
    int nidx = nb0 + qf*16 + lc;
    #pragma unroll
    for (int dh = 0; dh < 2; ++dh)
      #pragma unroll
      for (int r = 0; r < 4; ++r){
        int d = dh*16 + lq*4 + r;
        attn_o[(b*256 + h*32 + d)*NSP + nidx] = f2bf(O[qf][dh][r] * rl);
      }
    __syncthreads();
  }
}

// ---------------------------------------------------------------------------
// K7: out = wproj @ attn + bproj. fp32 GEMM, bf16 input. grid (36 nt, 4 ct, 4 b)
__global__ __launch_bounds__(256) void k7_proj(const unsigned short* __restrict__ attn_o,
    const float* __restrict__ wproj, const float* __restrict__ bproj,
    float* __restrict__ out){
  int nt = blockIdx.x, ct = blockIdx.y, b = blockIdx.z, t = threadIdx.x;
  int tc = t >> 4, tn = t & 15;
  __shared__ float xs[32][68];
  __shared__ float wsm[32][68];
  float acc[4][4];
  #pragma unroll
  for (int i = 0; i < 4; ++i)
    #pragma unroll
    for (int j = 0; j < 4; ++j) acc[i][j] = 0.f;
  for (int kc = 0; kc < 8; ++kc){
    __syncthreads();
    #pragma unroll
    for (int p2 = 0; p2 < 2; ++p2){
      int idx = t + 256*p2, k = idx >> 4, c4 = idx & 15;
      uvec2 u = *(const uvec2*)(attn_o + (b*256 + kc*32 + k)*NSP + nt*64 + c4*4);
      xs[k][c4*4+0] = bf2f((unsigned short)(u.x & 0xffffu));
      xs[k][c4*4+1] = bf2f((unsigned short)(u.x >> 16));
      xs[k][c4*4+2] = bf2f((unsigned short)(u.y & 0xffffu));
      xs[k][c4*4+3] = bf2f((unsigned short)(u.y >> 16));
    }
    #pragma unroll
    for (int p2 = 0; p2 < 2; ++p2){
      int idx = t + 256*p2, co = idx >> 3, c4 = idx & 7;
      fvec4 w4 = *(const fvec4*)(wproj + (ct*64 + co)*256 + kc*32 + c4*4);
      wsm[c4*4+0][co] = w4[0]; wsm[c4*4+1][co] = w4[1];
      wsm[c4*4+2][co] = w4[2]; wsm[c4*4+3][co] = w4[3];
    }
    __syncthreads();
    for (int k = 0; k < 32; ++k){
      fvec4 xv = *(fvec4*)&xs[k][tn*4];
      fvec4 w4 = *(fvec4*)&wsm[k][tc*4];
      #pragma unroll
      for (int i = 0; i < 4; ++i)
        #pragma unroll
        for (int j = 0; j < 4; ++j) acc[i][j] += w4[i]*xv[j];
    }
  }
  int n0 = nt*64 + tn*4;
  #pragma unroll
  for (int i = 0; i < 4; ++i){
    int co = ct*64 + tc*4 + i;
    float bp = bproj[co];
    fvec4 v; v[0] = acc[i][0]+bp; v[1] = acc[i][1]+bp; v[2] = acc[i][2]+bp; v[3] = acc[i][3]+bp;
    *(fvec4*)(out + (b*256 + co)*NSP + n0) = v;
  }
}

// ---------------------------------------------------------------------------
extern "C" void kernel_launch(void* const* d_in, const int* in_sizes, int n_in,
                              void* d_out, int out_size, void* d_ws, size_t ws_size,
                              hipStream_t stream) {
  const float* x     = (const float*)d_in[0];
  const float* rgb   = (const float*)d_in[1];
  const float* wq    = (const float*)d_in[2];
  const float* bq    = (const float*)d_in[3];
  const float* wk    = (const float*)d_in[4];
  const float* bk    = (const float*)d_in[5];
  const float* wv    = (const float*)d_in[6];
  const float* bv    = (const float*)d_in[7];
  const float* wproj = (const float*)d_in[8];
  const float* bproj = (const float*)d_in[9];
  const float* c1w   = (const float*)d_in[10];
  const float* c1b   = (const float*)d_in[11];
  const float* c2w   = (const float*)d_in[12];
  const float* c2b   = (const float*)d_in[13];
  const float* gq_w  = (const float*)d_in[14];
  const float* gq_b  = (const float*)d_in[15];
  const float* bqf_w = (const float*)d_in[16];
  const float* bqf_b = (const float*)d_in[17];
  const float* gk_w  = (const float*)d_in[18];
  const float* gk_b  = (const float*)d_in[19];
  const float* bkf_w = (const float*)d_in[20];
  const float* bkf_b = (const float*)d_in[21];
  const float* gv_w  = (const float*)d_in[22];
  const float* gv_b  = (const float*)d_in[23];
  const float* bvf_w = (const float*)d_in[24];
  const float* bvf_b = (const float*)d_in[25];
  const float* alphaP= (const float*)d_in[26];

  char* w = (char*)d_ws;
  float* luma_n = (float*)w;            w += 4*NSP*4;           // 36864
  float* bias_a = (float*)w;            w += 4*NSP*4;           // 36864
  float* hm_sum = (float*)w;            w += 512*4;             // 2048
  float* film   = (float*)w;            w += 6*4*256*4;         // 24576
  float* h1     = (float*)w;            w += 4*128*NSP*4;       // 4718592
  float* wt     = (float*)w;            w += 9*128*128*4;       // 589824
  unsigned short* q_t    = (unsigned short*)w; w += 4*8*NSP*32*2; // 4718592
  unsigned short* k_t    = (unsigned short*)w; w += 4*8*NSP*32*2;
  unsigned short* v_b    = (unsigned short*)w; w += 4*256*NSP*2;
  unsigned short* attn_o = (unsigned short*)w; w += 4*256*NSP*2;
  // total ~24.3 MB

  k1_luma <<<4, 256, 0, stream>>>(rgb, alphaP, luma_n, bias_a, hm_sum);
  k2_conv1<<<dim3(9,4,4), 256, 0, stream>>>(luma_n, c1w, c1b, h1);
  k2b_wt  <<<576, 256, 0, stream>>>(c2w, wt);
  k3_conv2<<<dim3(9,8,4), 256, 0, stream>>>(h1, wt, c2b, hm_sum);
  k4_film <<<24, 256, 0, stream>>>(hm_sum, gq_w, gq_b, bqf_w, bqf_b,
                                   gk_w, gk_b, bkf_w, bkf_b,
                                   gv_w, gv_b, bvf_w, bvf_b, film);
  k5_qkv  <<<dim3(36,4,4), 256, 0, stream>>>(x, wq, wk, wv, bq, bk, bv, film,
                                             q_t, k_t, v_b);
  k6_attn <<<dim3(18,8,4), 256, 0, stream>>>(q_t, k_t, v_b, bias_a, attn_o);
  k7_proj <<<dim3(36,4,4), 256, 0, stream>>>(attn_o, wproj, bproj, (float*)d_out);
}

// Round 2
// 382.695 us; speedup vs baseline: 1.4912x; 1.4912x over previous
//
#include <hip/hip_runtime.h>

// ---------------------------------------------------------------------------
// LuminanceAwareMHSA: B=4, C=256, H=W=48 (N=2304), HEADS=8, DH=32, HID=128
// Round 2: k3_conv2 rewritten as bf16 MFMA (was 227 us scalar, latency-bound,
// MfmaUtil=0). conv2 output is only consumed via its spatial mean, so k3 now
// computes relu(conv)+column-reduce directly into hm_sum atomics; the feature
// map is never materialized. conv1 writes a zero-padded bf16 h1p[b][50][50][128]
// so the 3x3 tap loop needs no boundary branches.
//   K1  luma + min/max norm + pooled-invL bias (also zeroes hm_sum)
//   K2  conv1 3x3 (1->128) + relu -> bf16 padded h1p
//   K2b transpose c2_w -> bf16 wtb[tap][oc][ic]
//   K3  conv2 via mfma_f32_16x16x32_bf16 + relu + column-sum -> hm_sum atomics
//   K4  FiLM params (6 small GEMVs)
//   K5  QKV GEMM + FiLM -> bf16 q_t/k_t [B,H,N,32] (SCALE folded into q)
//   K6  flash attention, mfma_f32_16x16x32_bf16, no-max online softmax
//   K7  output projection (fp32 GEMM, bf16 attn input) -> d_out
// ---------------------------------------------------------------------------

#define NSP 2304
#define WID 48

typedef __attribute__((ext_vector_type(4))) float  fvec4;
typedef __attribute__((ext_vector_type(2))) unsigned int uvec2;
typedef __attribute__((ext_vector_type(4))) unsigned int uvec4;
typedef __attribute__((ext_vector_type(8))) short  short8;   // 8 bf16 (4 VGPRs)
typedef __attribute__((ext_vector_type(4))) float  f32x4;    // MFMA C/D

__device__ inline unsigned short f2bf(float f){
  unsigned int u = __builtin_bit_cast(unsigned int, f);
  u += 0x7fffu + ((u >> 16) & 1u);           // RNE
  return (unsigned short)(u >> 16);
}
__device__ inline float bf2f(unsigned short h){
  unsigned int u = ((unsigned int)h) << 16;
  return __builtin_bit_cast(float, u);
}

// LDS swizzle helpers (keep write/read mappings consistent).
// kt: K tile [ml 0..63][d 0..31] bf16, 8-elem blocks xor-swizzled by (ml&3)
__device__ inline int kt_addr(int ml, int d){ return ml*32 + (((d>>3) ^ (ml&3))<<3) + (d&7); }
// vt: V tile [d 0..31][ml 0..63] bf16, 8-elem blocks xor-swizzled by (d&7)
__device__ inline int vt_addr(int d, int ml){ return d*64 + (((ml>>3) ^ (d&7))<<3) + (ml&7); }
// ps: P scratch [n 0..15][m 0..63] f32, 4-elem blocks xor-swizzled by (n&15)
__device__ inline int ps_addr(int n, int m){ return n*64 + ((((m>>2) ^ (n&15)))<<2) + (m&3); }

// ---------------------------------------------------------------------------
// K1: luma -> minmax-normalize; 3x3 zero-pad avg-pool of (1-luma); mean-center
//     and pre-multiply by alpha. Also zero hm_sum for K3's atomics.
__global__ void k1_luma(const float* __restrict__ rgb, const float* __restrict__ alphaP,
                        float* __restrict__ luma_n, float* __restrict__ bias_a,
                        float* __restrict__ hm_sum){
  int b = blockIdx.x, t = threadIdx.x;
  __shared__ float ly[NSP];
  __shared__ float ll[NSP];
  __shared__ float red[256];
  __shared__ float red2[256];
  const float* rp = rgb + b*3*NSP;
  float lmin = 1e30f, lmax = -1e30f;
  for (int i = t; i < NSP; i += 256){
    float y = 0.299f*rp[i] + 0.587f*rp[NSP+i] + 0.114f*rp[2*NSP+i];
    ly[i] = y; lmin = fminf(lmin, y); lmax = fmaxf(lmax, y);
  }
  red[t] = lmin; red2[t] = lmax;
  __syncthreads();
  for (int s = 128; s > 0; s >>= 1){
    if (t < s){ red[t] = fminf(red[t], red[t+s]); red2[t] = fmaxf(red2[t], red2[t+s]); }
    __syncthreads();
  }
  float mn = red[0], mx = red2[0];
  float inv = 1.0f / (mx - mn + 1e-6f);
  for (int i = t; i < NSP; i += 256){
    float v = (ly[i] - mn) * inv;
    ll[i] = v;
    luma_n[b*NSP + i] = v;
  }
  if (t < 128) hm_sum[b*128 + t] = 0.f;
  __syncthreads();
  float pr[9]; float psum = 0.f;
  #pragma unroll
  for (int ii = 0; ii < 9; ++ii){
    int n = t + 256*ii;
    int row = n / WID, col = n - row*WID;
    float s = 0.f;
    #pragma unroll
    for (int dy = -1; dy <= 1; ++dy)
      #pragma unroll
      for (int dx = -1; dx <= 1; ++dx){
        int r2 = row+dy, c2 = col+dx;
        if (r2 >= 0 && r2 < WID && c2 >= 0 && c2 < WID) s += 1.0f - ll[r2*WID + c2];
      }
    pr[ii] = s * (1.f/9.f);
    psum += pr[ii];
  }
  __syncthreads();
  red[t] = psum;
  __syncthreads();
  for (int s = 128; s > 0; s >>= 1){
    if (t < s) red[t] += red[t+s];
    __syncthreads();
  }
  float mean = red[0] * (1.f/(float)NSP);
  float alpha = alphaP[0];
  #pragma unroll
  for (int ii = 0; ii < 9; ++ii){
    int n = t + 256*ii;
    bias_a[b*NSP + n] = alpha * (pr[ii] - mean);
  }
}

// ---------------------------------------------------------------------------
// K2: conv1 3x3, 1 -> 128 channels, relu -> bf16 padded h1p[b][50*50][128].
// Interior only; pad ring pre-zeroed by hipMemsetAsync. grid (9 nt, 4 ocg, 4 b)
__global__ void k2_conv1(const float* __restrict__ luma_n, const float* __restrict__ c1w,
                         const float* __restrict__ c1b, unsigned short* __restrict__ h1p){
  int nt = blockIdx.x, ocg = blockIdx.y, b = blockIdx.z, t = threadIdx.x;
  __shared__ float wsm[32*9];
  __shared__ float bsm[32];
  for (int i = t; i < 288; i += 256) wsm[i] = c1w[ocg*288 + i];
  if (t < 32) bsm[t] = c1b[ocg*32 + t];
  __syncthreads();
  int n = nt*256 + t;
  int row = n / WID, col = n - row*WID;
  const float* lp = luma_n + b*NSP;
  float lv[9];
  int k = 0;
  #pragma unroll
  for (int dy = -1; dy <= 1; ++dy)
    #pragma unroll
    for (int dx = -1; dx <= 1; ++dx, ++k){
      int r2 = row+dy, c2 = col+dx;
      lv[k] = (r2 >= 0 && r2 < WID && c2 >= 0 && c2 < WID) ? lp[r2*WID + c2] : 0.f;
    }
  unsigned int packed[16];
  #pragma unroll
  for (int oc2 = 0; oc2 < 16; ++oc2){
    float a0 = bsm[oc2*2], a1 = bsm[oc2*2+1];
    #pragma unroll
    for (int q = 0; q < 9; ++q){
      a0 += wsm[(oc2*2)*9 + q] * lv[q];
      a1 += wsm[(oc2*2+1)*9 + q] * lv[q];
    }
    packed[oc2] = (unsigned)f2bf(fmaxf(a0, 0.f)) | ((unsigned)f2bf(fmaxf(a1, 0.f)) << 16);
  }
  unsigned short* dst = h1p + ((size_t)(b*2500 + (row+1)*50 + (col+1)))*128 + ocg*32;
  #pragma unroll
  for (int q4 = 0; q4 < 4; ++q4)
    *(uvec4*)(dst + q4*8) = *(uvec4*)&packed[q4*4];
}

// ---------------------------------------------------------------------------
// K2b: wtb[((tap*128)+oc)*128 + ic] = bf16(c2_w[oc][ic][tap])  (147456 elems)
__global__ void k2b_wt(const float* __restrict__ c2w, unsigned short* __restrict__ wtb){
  int idx = blockIdx.x*256 + threadIdx.x;
  int ic = idx & 127, rem = idx >> 7;
  int oc = rem & 127, tap = rem >> 7;
  wtb[idx] = f2bf(c2w[(oc*128 + ic)*9 + tap]);
}

// ---------------------------------------------------------------------------
// K3: conv2 128->128 as 9 shifted MFMA GEMMs + relu + column-sum -> hm_sum.
// Each block: one image row (48 cols) x 64 oc; wave = 16 oc x 48 cols.
// A = weights [m=oc][k=ic], B = h1p [k=ic][n=col], D[m=lq*4+r][n=lc].
// grid (48 rows, 2 ochalf, 4 b) = 384 blocks.
__global__ __launch_bounds__(256) void k3_conv2(const unsigned short* __restrict__ h1p,
    const unsigned short* __restrict__ wtb, const float* __restrict__ c2b,
    float* __restrict__ hm_sum){
  int row = blockIdx.x, mh = blockIdx.y, b = blockIdx.z;
  int t = threadIdx.x, wv = t >> 6, lane = t & 63;
  int lq = lane >> 4, lc = lane & 15;
  int ocb = mh*64 + wv*16;
  const f32x4 z4 = {0.f, 0.f, 0.f, 0.f};
  f32x4 C[3] = {z4, z4, z4};
  const unsigned short* hbase = h1p + (size_t)b*2500*128;
  #pragma unroll
  for (int tap = 0; tap < 9; ++tap){
    int dy = tap/3 - 1, dx = tap%3 - 1;
    const unsigned short* wrow = wtb + (tap*128 + ocb + lc)*128 + lq*8;
    const unsigned short* hrow = hbase + ((row+dy+1)*50 + (dx+1) + lc)*128 + lq*8;
    #pragma unroll
    for (int kc = 0; kc < 4; ++kc){
      short8 aW = *(const short8*)(wrow + kc*32);
      #pragma unroll
      for (int ntp = 0; ntp < 3; ++ntp){
        short8 bH = *(const short8*)(hrow + ntp*16*128 + kc*32);
        C[ntp] = __builtin_amdgcn_mfma_f32_16x16x32_bf16(aW, bH, C[ntp], 0, 0, 0);
      }
    }
  }
  // relu(conv+bias), sum over this row's 48 cols, atomicAdd per oc
  float s[4];
  #pragma unroll
  for (int r = 0; r < 4; ++r){
    float bias = c2b[ocb + lq*4 + r];
    float v = 0.f;
    #pragma unroll
    for (int ntp = 0; ntp < 3; ++ntp) v += fmaxf(C[ntp][r] + bias, 0.f);
    v += __shfl_xor(v, 1, 64);
    v += __shfl_xor(v, 2, 64);
    v += __shfl_xor(v, 4, 64);
    v += __shfl_xor(v, 8, 64);
    s[r] = v;
  }
  if (lc == 0){
    #pragma unroll
    for (int r = 0; r < 4; ++r)
      atomicAdd(&hm_sum[b*128 + ocb + lq*4 + r], s[r]);
  }
}

// ---------------------------------------------------------------------------
// K4: FiLM params. film[(m6*4 + b)*256 + o], m6: 0=gq 1=bqf 2=gk 3=bkf 4=gv 5=bvf
__global__ void k4_film(const float* __restrict__ hm_sum,
  const float* w0, const float* b0, const float* w1, const float* b1,
  const float* w2, const float* b2, const float* w3, const float* b3,
  const float* w4, const float* b4, const float* w5, const float* b5,
  float* __restrict__ film){
  __shared__ float hs[128];
  int bb = blockIdx.x & 3, m6 = blockIdx.x >> 2, t = threadIdx.x;
  if (t < 128) hs[t] = hm_sum[bb*128 + t] * (1.f/(float)NSP);
  __syncthreads();
  const float* wm[6] = {w0,w1,w2,w3,w4,w5};
  const float* bm[6] = {b0,b1,b2,b3,b4,b5};
  const float* w = wm[m6];
  int o = t;
  float a = bm[m6][o];
  for (int h2 = 0; h2 < 128; ++h2) a += hs[h2] * w[o*128 + h2];
  film[blockIdx.x*256 + t] = a;
}

// ---------------------------------------------------------------------------
// K5: q/k/v = FiLM(x @ w^T + b). fp32 tiled GEMM (64o x 64n per block, all 3
// projections share the staged x tile). Emits bf16: q_t,k_t [B,8,N,32]
// (SCALE folded into q), v [B,256,N]. grid (36 nt, 4 ot, 4 b).
__global__ __launch_bounds__(256) void k5_qkv(const float* __restrict__ x,
    const float* __restrict__ wq, const float* __restrict__ wk, const float* __restrict__ wv_,
    const float* __restrict__ bq, const float* __restrict__ bk, const float* __restrict__ bv,
    const float* __restrict__ film,
    unsigned short* __restrict__ q_t, unsigned short* __restrict__ k_t,
    unsigned short* __restrict__ v_b){
  int nt = blockIdx.x, ot = blockIdx.y, b = blockIdx.z, t = threadIdx.x;
  int to = t >> 4, tn = t & 15;
  __shared__ float xs[32][68];
  __shared__ float wsm[3][32][68];
  float acc[3][4][4];
  #pragma unroll
  for (int p = 0; p < 3; ++p)
    #pragma unroll
    for (int i = 0; i < 4; ++i)
      #pragma unroll
      for (int j = 0; j < 4; ++j) acc[p][i][j] = 0.f;
  const float* wmats[3] = {wq, wk, wv_};
  for (int kc = 0; kc < 8; ++kc){
    __syncthreads();
    #pragma unroll
    for (int p2 = 0; p2 < 2; ++p2){
      int idx = t + 256*p2, k = idx >> 4, c4 = idx & 15;
      fvec4 xv = *(const fvec4*)(x + (b*256 + kc*32 + k)*NSP + nt*64 + c4*4);
      *(fvec4*)&xs[k][c4*4] = xv;
    }
    #pragma unroll
    for (int p = 0; p < 3; ++p){
      #pragma unroll
      for (int p2 = 0; p2 < 2; ++p2){
        int idx = t + 256*p2, o = idx >> 3, c4 = idx & 7;
        fvec4 w4 = *(const fvec4*)(wmats[p] + (ot*64 + o)*256 + kc*32 + c4*4);
        wsm[p][c4*4+0][o] = w4[0]; wsm[p][c4*4+1][o] = w4[1];
        wsm[p][c4*4+2][o] = w4[2]; wsm[p][c4*4+3][o] = w4[3];
      }
    }
    __syncthreads();
    for (int k = 0; k < 32; ++k){
      fvec4 xv = *(fvec4*)&xs[k][tn*4];
      #pragma unroll
      for (int p = 0; p < 3; ++p){
        fvec4 w4 = *(fvec4*)&wsm[p][k][to*4];
        #pragma unroll
        for (int i = 0; i < 4; ++i)
          #pragma unroll
          for (int j = 0; j < 4; ++j) acc[p][i][j] += w4[i]*xv[j];
      }
    }
  }
  const float* bvecs[3] = {bq, bk, bv};
  int obase = ot*64 + to*4;
  #pragma unroll
  for (int p = 0; p < 3; ++p){
    float vals[4][4];
    #pragma unroll
    for (int i = 0; i < 4; ++i){
      int o = obase + i;
      float g  = film[(2*p*4 + b)*256 + o];
      float bt = film[((2*p+1)*4 + b)*256 + o];
      float bz = bvecs[p][o];
      #pragma unroll
      for (int j = 0; j < 4; ++j){
        float val = g*(acc[p][i][j] + bz) + bt;
        if (p == 0) val *= 0.17677669529663687f;  // SCALE = DH^-0.5
        vals[i][j] = val;
      }
    }
    if (p < 2){
      unsigned short* dst = (p == 0) ? q_t : k_t;
      int hh = obase >> 5, d0 = obase & 31;
      #pragma unroll
      for (int j = 0; j < 4; ++j){
        int n = nt*64 + tn*4 + j;
        uvec2 u;
        u.x = (unsigned)f2bf(vals[0][j]) | ((unsigned)f2bf(vals[1][j]) << 16);
        u.y = (unsigned)f2bf(vals[2][j]) | ((unsigned)f2bf(vals[3][j]) << 16);
        *(uvec2*)(dst + ((b*8 + hh)*NSP + n)*32 + d0) = u;
      }
    } else {
      int n0 = nt*64 + tn*4;
      #pragma unroll
      for (int i = 0; i < 4; ++i){
        int o = obase + i;
        uvec2 u;
        u.x = (unsigned)f2bf(vals[i][0]) | ((unsigned)f2bf(vals[i][1]) << 16);
        u.y = (unsigned)f2bf(vals[i][2]) | ((unsigned)f2bf(vals[i][3]) << 16);
        *(uvec2*)(v_b + (b*256 + o)*NSP + n0) = u;
      }
    }
  }
}

// ---------------------------------------------------------------------------
// K6: flash attention, mfma_f32_16x16x32_bf16, no-max online softmax.
// Block: 4 waves x 32 queries = 128 queries. m-loop tiles of 64 keys.
// Layouts (verified per guide): A[m=lane&15][k=(lane>>4)*8+j],
// B[k=(lane>>4)*8+j][n=lane&15], D[row=(lane>>4)*4+reg][col=lane&15].
// grid (18 qblk, 8 h, 4 b).
__global__ __launch_bounds__(256) void k6_attn(const unsigned short* __restrict__ q_t,
    const unsigned short* __restrict__ k_t, const unsigned short* __restrict__ v_b,
    const float* __restrict__ bias_a, unsigned short* __restrict__ attn_o){
  int qblk = blockIdx.x, h = blockIdx.y, b = blockIdx.z;
  int t = threadIdx.x, wv = t >> 6, lane = t & 63;
  int lq = lane >> 4, lc = lane & 15;
  __shared__ unsigned short kt[64*32];
  __shared__ unsigned short vt[32*64];
  __shared__ float ps[4][16*64];     // per-wave P scratch (swizzled)
  __shared__ float lbuf[4][2][16];
  int bh = b*8 + h;
  const f32x4 z4 = {0.f, 0.f, 0.f, 0.f};
  short8 aQ[2];
  int nb0 = qblk*128 + wv*32;
  #pragma unroll
  for (int qf = 0; qf < 2; ++qf){
    const unsigned short* qp = q_t + (bh*NSP + nb0 + qf*16 + lc)*32 + lq*8;
    aQ[qf] = *(const short8*)qp;
  }
  f32x4 O[2][2];
  float lpart[2][4];
  #pragma unroll
  for (int qf = 0; qf < 2; ++qf){
    #pragma unroll
    for (int dh = 0; dh < 2; ++dh) O[qf][dh] = z4;
    #pragma unroll
    for (int r = 0; r < 4; ++r) lpart[qf][r] = 0.f;
  }
  const float* brow = bias_a + b*NSP;
  float* myps = ps[wv];

  for (int m0 = 0; m0 < NSP; m0 += 64){
    __syncthreads();
    // stage K tile [64m][32d] (swizzled)
    #pragma unroll
    for (int p2 = 0; p2 < 2; ++p2){
      int ml = (t >> 3) + 32*p2, ch = t & 7;
      uvec2 d2 = *(const uvec2*)(k_t + (bh*NSP + m0 + ml)*32 + ch*4);
      *(uvec2*)&kt[kt_addr(ml, ch*4)] = d2;
    }
    // stage V tile [32d][64m] (swizzled)
    #pragma unroll
    for (int p2 = 0; p2 < 2; ++p2){
      int d = (t >> 4) + 16*p2, c16 = t & 15;
      uvec2 d2 = *(const uvec2*)(v_b + (b*256 + h*32 + d)*NSP + m0 + c16*4);
      *(uvec2*)&vt[vt_addr(d, c16*4)] = d2;
    }
    __syncthreads();
    // V A-fragments (shared by both q-frags)
    short8 aV[2][2];
    #pragma unroll
    for (int dh = 0; dh < 2; ++dh)
      #pragma unroll
      for (int mh = 0; mh < 2; ++mh)
        aV[dh][mh] = *(const short8*)&vt[vt_addr(dh*16 + lc, mh*32 + lq*8)];
    #pragma unroll
    for (int qf = 0; qf < 2; ++qf){
      // S = Q^T K (4 x 16 key-cols)
      f32x4 S[4];
      #pragma unroll
      for (int g = 0; g < 4; ++g){
        short8 bK = *(const short8*)&kt[kt_addr(g*16 + lc, lq*8)];
        S[g] = __builtin_amdgcn_mfma_f32_16x16x32_bf16(aQ[qf], bK, z4, 0, 0, 0);
      }
      // P = exp(S + bias[m]); accumulate row-sum partials; scratch in swizzled LDS
      #pragma unroll
      for (int g = 0; g < 4; ++g){
        float bias = brow[m0 + g*16 + lc];
        #pragma unroll
        for (int r = 0; r < 4; ++r){
          float p = __expf(S[g][r] + bias);
          lpart[qf][r] += p;
          myps[ps_addr(lq*4 + r, g*16 + lc)] = p;
        }
      }
      // PV: O^T[d][n] += V[d][m] * P^T[m][n]
      #pragma unroll
      for (int mh = 0; mh < 2; ++mh){
        fvec4 p0 = *(fvec4*)&myps[ps_addr(lc, mh*32 + lq*8)];
        fvec4 p1 = *(fvec4*)&myps[ps_addr(lc, mh*32 + lq*8 + 4)];
        short8 bP;
        bP[0] = (short)f2bf(p0[0]); bP[1] = (short)f2bf(p0[1]);
        bP[2] = (short)f2bf(p0[2]); bP[3] = (short)f2bf(p0[3]);
        bP[4] = (short)f2bf(p1[0]); bP[5] = (short)f2bf(p1[1]);
        bP[6] = (short)f2bf(p1[2]); bP[7] = (short)f2bf(p1[3]);
        #pragma unroll
        for (int dh = 0; dh < 2; ++dh)
          O[qf][dh] = __builtin_amdgcn_mfma_f32_16x16x32_bf16(aV[dh][mh], bP, O[qf][dh], 0, 0, 0);
      }
    }
  }
  // epilogue: row sums across the 16 lanes of each quad, normalize, store bf16
  #pragma unroll
  for (int qf = 0; qf < 2; ++qf){
    #pragma unroll
    for (int r = 0; r < 4; ++r){
      float lv = lpart[qf][r];
      lv += __shfl_xor(lv, 1, 64);
      lv += __shfl_xor(lv, 2, 64);
      lv += __shfl_xor(lv, 4, 64);
      lv += __shfl_xor(lv, 8, 64);
      if (lc == 0) lbuf[wv][qf][lq*4 + r] = lv;
    }
    __syncthreads();
    float rl = 1.0f / lbuf[wv][qf][lc];
    int nidx = nb0 + qf*16 + lc;
    #pragma unroll
    for (int dh = 0; dh < 2; ++dh)
      #pragma unroll
      for (int r = 0; r < 4; ++r){
        int d = dh*16 + lq*4 + r;
        attn_o[(b*256 + h*32 + d)*NSP + nidx] = f2bf(O[qf][dh][r] * rl);
      }
    __syncthreads();
  }
}

// ---------------------------------------------------------------------------
// K7: out = wproj @ attn + bproj. fp32 GEMM, bf16 input. grid (36 nt, 4 ct, 4 b)
__global__ __launch_bounds__(256) void k7_proj(const unsigned short* __restrict__ attn_o,
    const float* __restrict__ wproj, const float* __restrict__ bproj,
    float* __restrict__ out){
  int nt = blockIdx.x, ct = blockIdx.y, b = blockIdx.z, t = threadIdx.x;
  int tc = t >> 4, tn = t & 15;
  __shared__ float xs[32][68];
  __shared__ float wsm[32][68];
  float acc[4][4];
  #pragma unroll
  for (int i = 0; i < 4; ++i)
    #pragma unroll
    for (int j = 0; j < 4; ++j) acc[i][j] = 0.f;
  for (int kc = 0; kc < 8; ++kc){
    __syncthreads();
    #pragma unroll
    for (int p2 = 0; p2 < 2; ++p2){
      int idx = t + 256*p2, k = idx >> 4, c4 = idx & 15;
      uvec2 u = *(const uvec2*)(attn_o + (b*256 + kc*32 + k)*NSP + nt*64 + c4*4);
      xs[k][c4*4+0] = bf2f((unsigned short)(u.x & 0xffffu));
      xs[k][c4*4+1] = bf2f((unsigned short)(u.x >> 16));
      xs[k][c4*4+2] = bf2f((unsigned short)(u.y & 0xffffu));
      xs[k][c4*4+3] = bf2f((unsigned short)(u.y >> 16));
    }
    #pragma unroll
    for (int p2 = 0; p2 < 2; ++p2){
      int idx = t + 256*p2, co = idx >> 3, c4 = idx & 7;
      fvec4 w4 = *(const fvec4*)(wproj + (ct*64 + co)*256 + kc*32 + c4*4);
      wsm[c4*4+0][co] = w4[0]; wsm[c4*4+1][co] = w4[1];
      wsm[c4*4+2][co] = w4[2]; wsm[c4*4+3][co] = w4[3];
    }
    __syncthreads();
    for (int k = 0; k < 32; ++k){
      fvec4 xv = *(fvec4*)&xs[k][tn*4];
      fvec4 w4 = *(fvec4*)&wsm[k][tc*4];
      #pragma unroll
      for (int i = 0; i < 4; ++i)
        #pragma unroll
        for (int j = 0; j < 4; ++j) acc[i][j] += w4[i]*xv[j];
    }
  }
  int n0 = nt*64 + tn*4;
  #pragma unroll
  for (int i = 0; i < 4; ++i){
    int co = ct*64 + tc*4 + i;
    float bp = bproj[co];
    fvec4 v; v[0] = acc[i][0]+bp; v[1] = acc[i][1]+bp; v[2] = acc[i][2]+bp; v[3] = acc[i][3]+bp;
    *(fvec4*)(out + (b*256 + co)*NSP + n0) = v;
  }
}

// ---------------------------------------------------------------------------
extern "C" void kernel_launch(void* const* d_in, const int* in_sizes, int n_in,
                              void* d_out, int out_size, void* d_ws, size_t ws_size,
                              hipStream_t stream) {
  const float* x     = (const float*)d_in[0];
  const float* rgb   = (const float*)d_in[1];
  const float* wq    = (const float*)d_in[2];
  const float* bq    = (const float*)d_in[3];
  const float* wk    = (const float*)d_in[4];
  const float* bk    = (const float*)d_in[5];
  const float* wv    = (const float*)d_in[6];
  const float* bv    = (const float*)d_in[7];
  const float* wproj = (const float*)d_in[8];
  const float* bproj = (const float*)d_in[9];
  const float* c1w   = (const float*)d_in[10];
  const float* c1b   = (const float*)d_in[11];
  const float* c2w   = (const float*)d_in[12];
  const float* c2b   = (const float*)d_in[13];
  const float* gq_w  = (const float*)d_in[14];
  const float* gq_b  = (const float*)d_in[15];
  const float* bqf_w = (const float*)d_in[16];
  const float* bqf_b = (const float*)d_in[17];
  const float* gk_w  = (const float*)d_in[18];
  const float* gk_b  = (const float*)d_in[19];
  const float* bkf_w = (const float*)d_in[20];
  const float* bkf_b = (const float*)d_in[21];
  const float* gv_w  = (const float*)d_in[22];
  const float* gv_b  = (const float*)d_in[23];
  const float* bvf_w = (const float*)d_in[24];
  const float* bvf_b = (const float*)d_in[25];
  const float* alphaP= (const float*)d_in[26];

  char* w = (char*)d_ws;
  float* luma_n = (float*)w;            w += 4*NSP*4;             // 36864
  float* bias_a = (float*)w;            w += 4*NSP*4;             // 36864
  float* hm_sum = (float*)w;            w += 512*4;               // 2048
  float* film   = (float*)w;            w += 6*4*256*4;           // 24576
  unsigned short* h1p = (unsigned short*)w; w += 4*2500*128*2;    // 2,560,000 (padded bf16)
  unsigned short* wtb = (unsigned short*)w; w += 9*128*128*2;     // 294,912
  unsigned short* q_t    = (unsigned short*)w; w += 4*8*NSP*32*2; // 4,718,592
  unsigned short* k_t    = (unsigned short*)w; w += 4*8*NSP*32*2;
  unsigned short* v_b    = (unsigned short*)w; w += 4*256*NSP*2;
  unsigned short* attn_o = (unsigned short*)w; w += 4*256*NSP*2;
  // total ~17.5 MB

  hipMemsetAsync(h1p, 0, (size_t)4*2500*128*2, stream);  // zero pad ring
  k1_luma <<<4, 256, 0, stream>>>(rgb, alphaP, luma_n, bias_a, hm_sum);
  k2_conv1<<<dim3(9,4,4), 256, 0, stream>>>(luma_n, c1w, c1b, h1p);
  k2b_wt  <<<576, 256, 0, stream>>>(c2w, wtb);
  k3_conv2<<<dim3(48,2,4), 256, 0, stream>>>(h1p, wtb, c2b, hm_sum);
  k4_film <<<24, 256, 0, stream>>>(hm_sum, gq_w, gq_b, bqf_w, bqf_b,
                                   gk_w, gk_b, bkf_w, bkf_b,
                                   gv_w, gv_b, bvf_w, bvf_b, film);
  k5_qkv  <<<dim3(36,4,4), 256, 0, stream>>>(x, wq, wk, wv, bq, bk, bv, film,
                                             q_t, k_t, v_b);
  k6_attn <<<dim3(18,8,4), 256, 0, stream>>>(q_t, k_t, v_b, bias_a, attn_o);
  k7_proj <<<dim3(36,4,4), 256, 0, stream>>>(attn_o, wproj, bproj, (float*)d_out);
}

// Round 5
// 347.382 us; speedup vs baseline: 1.6428x; 1.1017x over previous
//
#include <hip/hip_runtime.h>

// ---------------------------------------------------------------------------
// LuminanceAwareMHSA: B=4, C=256, H=W=48 (N=2304), HEADS=8, DH=32, HID=128
// Round 5: k6 P^T->B-layout transpose via per-wave LDS scratch (barrier-free)
// -- the round-4 ds_bpermute routing was provably wrong (2 bpermutes cannot
// express the needed permutation; dest lq=1/2 got swapped key groups).
// Everything else as round 3/4: S^T = K*Q^T via MFMA operand swap, bias via
// MFMA C-init, row-sum l via ones-MFMA, exp2 with log2e folded into q (K5)
// and bias (K1), split-K=2 with f32 partials combined+normalized in K7.
//   K1  luma + min/max norm + pooled-invL bias (pre-scaled alpha*log2e)
//   K2  conv1 3x3 (1->128) + relu -> bf16 padded h1p
//   K2b transpose c2_w -> bf16 wtb[tap][oc][ic]
//   K3  conv2 via mfma + relu + column-sum -> hm_sum atomics
//   K4  FiLM params (6 small GEMVs)
//   K5  QKV GEMM + FiLM -> bf16 q_t/k_t [B,H,N,32] (SCALE*log2e in q)
//   K6  flash attention (split-K=2, per-wave LDS, no barriers) -> f32 o/l
//   K7  combine splits + normalize + output projection -> d_out
// ---------------------------------------------------------------------------

#define NSP 2304
#define WID 48

typedef __attribute__((ext_vector_type(4))) float  fvec4;
typedef __attribute__((ext_vector_type(2))) unsigned int uvec2;
typedef __attribute__((ext_vector_type(4))) unsigned int uvec4;
typedef __attribute__((ext_vector_type(8))) short  short8;   // 8 bf16 (4 VGPRs)
typedef __attribute__((ext_vector_type(4))) float  f32x4;    // MFMA C/D

__device__ inline unsigned short f2bf(float f){
  unsigned int u = __builtin_bit_cast(unsigned int, f);
  u += 0x7fffu + ((u >> 16) & 1u);           // RNE
  return (unsigned short)(u >> 16);
}
__device__ inline unsigned pack2bf(float a, float b){
  return (unsigned)f2bf(a) | ((unsigned)f2bf(b) << 16);
}

// ---------------------------------------------------------------------------
// K1: luma -> minmax-normalize; 3x3 zero-pad avg-pool of (1-luma); mean-center
//     and pre-multiply by alpha*log2e (k6 uses exp2). Also zero hm_sum.
__global__ void k1_luma(const float* __restrict__ rgb, const float* __restrict__ alphaP,
                        float* __restrict__ luma_n, float* __restrict__ bias_a,
                        float* __restrict__ hm_sum){
  int b = blockIdx.x, t = threadIdx.x;
  __shared__ float ly[NSP];
  __shared__ float ll[NSP];
  __shared__ float red[256];
  __shared__ float red2[256];
  const float* rp = rgb + b*3*NSP;
  float lmin = 1e30f, lmax = -1e30f;
  for (int i = t; i < NSP; i += 256){
    float y = 0.299f*rp[i] + 0.587f*rp[NSP+i] + 0.114f*rp[2*NSP+i];
    ly[i] = y; lmin = fminf(lmin, y); lmax = fmaxf(lmax, y);
  }
  red[t] = lmin; red2[t] = lmax;
  __syncthreads();
  for (int s = 128; s > 0; s >>= 1){
    if (t < s){ red[t] = fminf(red[t], red[t+s]); red2[t] = fmaxf(red2[t], red2[t+s]); }
    __syncthreads();
  }
  float mn = red[0], mx = red2[0];
  float inv = 1.0f / (mx - mn + 1e-6f);
  for (int i = t; i < NSP; i += 256){
    float v = (ly[i] - mn) * inv;
    ll[i] = v;
    luma_n[b*NSP + i] = v;
  }
  if (t < 128) hm_sum[b*128 + t] = 0.f;
  __syncthreads();
  float pr[9]; float psum = 0.f;
  #pragma unroll
  for (int ii = 0; ii < 9; ++ii){
    int n = t + 256*ii;
    int row = n / WID, col = n - row*WID;
    float s = 0.f;
    #pragma unroll
    for (int dy = -1; dy <= 1; ++dy)
      #pragma unroll
      for (int dx = -1; dx <= 1; ++dx){
        int r2 = row+dy, c2 = col+dx;
        if (r2 >= 0 && r2 < WID && c2 >= 0 && c2 < WID) s += 1.0f - ll[r2*WID + c2];
      }
    pr[ii] = s * (1.f/9.f);
    psum += pr[ii];
  }
  __syncthreads();
  red[t] = psum;
  __syncthreads();
  for (int s = 128; s > 0; s >>= 1){
    if (t < s) red[t] += red[t+s];
    __syncthreads();
  }
  float mean = red[0] * (1.f/(float)NSP);
  float alpha = alphaP[0] * 1.4426950408889634f;   // fold log2(e) for exp2
  #pragma unroll
  for (int ii = 0; ii < 9; ++ii){
    int n = t + 256*ii;
    bias_a[b*NSP + n] = alpha * (pr[ii] - mean);
  }
}

// ---------------------------------------------------------------------------
// K2: conv1 3x3, 1 -> 128 channels, relu -> bf16 padded h1p[b][50*50][128].
__global__ void k2_conv1(const float* __restrict__ luma_n, const float* __restrict__ c1w,
                         const float* __restrict__ c1b, unsigned short* __restrict__ h1p){
  int nt = blockIdx.x, ocg = blockIdx.y, b = blockIdx.z, t = threadIdx.x;
  __shared__ float wsm[32*9];
  __shared__ float bsm[32];
  for (int i = t; i < 288; i += 256) wsm[i] = c1w[ocg*288 + i];
  if (t < 32) bsm[t] = c1b[ocg*32 + t];
  __syncthreads();
  int n = nt*256 + t;
  int row = n / WID, col = n - row*WID;
  const float* lp = luma_n + b*NSP;
  float lv[9];
  int k = 0;
  #pragma unroll
  for (int dy = -1; dy <= 1; ++dy)
    #pragma unroll
    for (int dx = -1; dx <= 1; ++dx, ++k){
      int r2 = row+dy, c2 = col+dx;
      lv[k] = (r2 >= 0 && r2 < WID && c2 >= 0 && c2 < WID) ? lp[r2*WID + c2] : 0.f;
    }
  unsigned int packed[16];
  #pragma unroll
  for (int oc2 = 0; oc2 < 16; ++oc2){
    float a0 = bsm[oc2*2], a1 = bsm[oc2*2+1];
    #pragma unroll
    for (int q = 0; q < 9; ++q){
      a0 += wsm[(oc2*2)*9 + q] * lv[q];
      a1 += wsm[(oc2*2+1)*9 + q] * lv[q];
    }
    packed[oc2] = pack2bf(fmaxf(a0, 0.f), fmaxf(a1, 0.f));
  }
  unsigned short* dst = h1p + ((size_t)(b*2500 + (row+1)*50 + (col+1)))*128 + ocg*32;
  #pragma unroll
  for (int q4 = 0; q4 < 4; ++q4)
    *(uvec4*)(dst + q4*8) = *(uvec4*)&packed[q4*4];
}

// ---------------------------------------------------------------------------
// K2b: wtb[((tap*128)+oc)*128 + ic] = bf16(c2_w[oc][ic][tap])
__global__ void k2b_wt(const float* __restrict__ c2w, unsigned short* __restrict__ wtb){
  int idx = blockIdx.x*256 + threadIdx.x;
  int ic = idx & 127, rem = idx >> 7;
  int oc = rem & 127, tap = rem >> 7;
  wtb[idx] = f2bf(c2w[(oc*128 + ic)*9 + tap]);
}

// ---------------------------------------------------------------------------
// K3: conv2 128->128 as 9 shifted MFMA GEMMs + relu + column-sum -> hm_sum.
__global__ __launch_bounds__(256) void k3_conv2(const unsigned short* __restrict__ h1p,
    const unsigned short* __restrict__ wtb, const float* __restrict__ c2b,
    float* __restrict__ hm_sum){
  int row = blockIdx.x, mh = blockIdx.y, b = blockIdx.z;
  int t = threadIdx.x, wv = t >> 6, lane = t & 63;
  int lq = lane >> 4, lc = lane & 15;
  int ocb = mh*64 + wv*16;
  const f32x4 z4 = {0.f, 0.f, 0.f, 0.f};
  f32x4 C[3] = {z4, z4, z4};
  const unsigned short* hbase = h1p + (size_t)b*2500*128;
  #pragma unroll
  for (int tap = 0; tap < 9; ++tap){
    int dy = tap/3 - 1, dx = tap%3 - 1;
    const unsigned short* wrow = wtb + (tap*128 + ocb + lc)*128 + lq*8;
    const unsigned short* hrow = hbase + ((row+dy+1)*50 + (dx+1) + lc)*128 + lq*8;
    #pragma unroll
    for (int kc = 0; kc < 4; ++kc){
      short8 aW = *(const short8*)(wrow + kc*32);
      #pragma unroll
      for (int ntp = 0; ntp < 3; ++ntp){
        short8 bH = *(const short8*)(hrow + ntp*16*128 + kc*32);
        C[ntp] = __builtin_amdgcn_mfma_f32_16x16x32_bf16(aW, bH, C[ntp], 0, 0, 0);
      }
    }
  }
  float s[4];
  #pragma unroll
  for (int r = 0; r < 4; ++r){
    float bias = c2b[ocb + lq*4 + r];
    float v = 0.f;
    #pragma unroll
    for (int ntp = 0; ntp < 3; ++ntp) v += fmaxf(C[ntp][r] + bias, 0.f);
    v += __shfl_xor(v, 1, 64);
    v += __shfl_xor(v, 2, 64);
    v += __shfl_xor(v, 4, 64);
    v += __shfl_xor(v, 8, 64);
    s[r] = v;
  }
  if (lc == 0){
    #pragma unroll
    for (int r = 0; r < 4; ++r)
      atomicAdd(&hm_sum[b*128 + ocb + lq*4 + r], s[r]);
  }
}

// ---------------------------------------------------------------------------
// K4: FiLM params. film[(m6*4 + b)*256 + o]
__global__ void k4_film(const float* __restrict__ hm_sum,
  const float* w0, const float* b0, const float* w1, const float* b1,
  const float* w2, const float* b2, const float* w3, const float* b3,
  const float* w4, const float* b4, const float* w5, const float* b5,
  float* __restrict__ film){
  __shared__ float hs[128];
  int bb = blockIdx.x & 3, m6 = blockIdx.x >> 2, t = threadIdx.x;
  if (t < 128) hs[t] = hm_sum[bb*128 + t] * (1.f/(float)NSP);
  __syncthreads();
  const float* wm[6] = {w0,w1,w2,w3,w4,w5};
  const float* bm[6] = {b0,b1,b2,b3,b4,b5};
  const float* w = wm[m6];
  int o = t;
  float a = bm[m6][o];
  for (int h2 = 0; h2 < 128; ++h2) a += hs[h2] * w[o*128 + h2];
  film[blockIdx.x*256 + t] = a;
}

// ---------------------------------------------------------------------------
// K5: q/k/v = FiLM(x @ w^T + b). fp32 tiled GEMM. Emits bf16 q_t,k_t
// [B,8,N,32] (SCALE*log2e folded into q), v [B,256,N]. grid (36,4,4).
__global__ __launch_bounds__(256) void k5_qkv(const float* __restrict__ x,
    const float* __restrict__ wq, const float* __restrict__ wk, const float* __restrict__ wv_,
    const float* __restrict__ bq, const float* __restrict__ bk, const float* __restrict__ bv,
    const float* __restrict__ film,
    unsigned short* __restrict__ q_t, unsigned short* __restrict__ k_t,
    unsigned short* __restrict__ v_b){
  int nt = blockIdx.x, ot = blockIdx.y, b = blockIdx.z, t = threadIdx.x;
  int to = t >> 4, tn = t & 15;
  __shared__ float xs[32][68];
  __shared__ float wsm[3][32][68];
  float acc[3][4][4];
  #pragma unroll
  for (int p = 0; p < 3; ++p)
    #pragma unroll
    for (int i = 0; i < 4; ++i)
      #pragma unroll
      for (int j = 0; j < 4; ++j) acc[p][i][j] = 0.f;
  const float* wmats[3] = {wq, wk, wv_};
  for (int kc = 0; kc < 8; ++kc){
    __syncthreads();
    #pragma unroll
    for (int p2 = 0; p2 < 2; ++p2){
      int idx = t + 256*p2, k = idx >> 4, c4 = idx & 15;
      fvec4 xv = *(const fvec4*)(x + (b*256 + kc*32 + k)*NSP + nt*64 + c4*4);
      *(fvec4*)&xs[k][c4*4] = xv;
    }
    #pragma unroll
    for (int p = 0; p < 3; ++p){
      #pragma unroll
      for (int p2 = 0; p2 < 2; ++p2){
        int idx = t + 256*p2, o = idx >> 3, c4 = idx & 7;
        fvec4 w4 = *(const fvec4*)(wmats[p] + (ot*64 + o)*256 + kc*32 + c4*4);
        wsm[p][c4*4+0][o] = w4[0]; wsm[p][c4*4+1][o] = w4[1];
        wsm[p][c4*4+2][o] = w4[2]; wsm[p][c4*4+3][o] = w4[3];
      }
    }
    __syncthreads();
    for (int k = 0; k < 32; ++k){
      fvec4 xv = *(fvec4*)&xs[k][tn*4];
      #pragma unroll
      for (int p = 0; p < 3; ++p){
        fvec4 w4 = *(fvec4*)&wsm[p][k][to*4];
        #pragma unroll
        for (int i = 0; i < 4; ++i)
          #pragma unroll
          for (int j = 0; j < 4; ++j) acc[p][i][j] += w4[i]*xv[j];
      }
    }
  }
  const float* bvecs[3] = {bq, bk, bv};
  int obase = ot*64 + to*4;
  #pragma unroll
  for (int p = 0; p < 3; ++p){
    float vals[4][4];
    #pragma unroll
    for (int i = 0; i < 4; ++i){
      int o = obase + i;
      float g  = film[(2*p*4 + b)*256 + o];
      float bt = film[((2*p+1)*4 + b)*256 + o];
      float bz = bvecs[p][o];
      #pragma unroll
      for (int j = 0; j < 4; ++j){
        float val = g*(acc[p][i][j] + bz) + bt;
        if (p == 0) val *= 0.17677669529663687f * 1.4426950408889634f;  // SCALE*log2e
        vals[i][j] = val;
      }
    }
    if (p < 2){
      unsigned short* dst = (p == 0) ? q_t : k_t;
      int hh = obase >> 5, d0 = obase & 31;
      #pragma unroll
      for (int j = 0; j < 4; ++j){
        int n = nt*64 + tn*4 + j;
        uvec2 u;
        u.x = pack2bf(vals[0][j], vals[1][j]);
        u.y = pack2bf(vals[2][j], vals[3][j]);
        *(uvec2*)(dst + ((b*8 + hh)*NSP + n)*32 + d0) = u;
      }
    } else {
      int n0 = nt*64 + tn*4;
      #pragma unroll
      for (int i = 0; i < 4; ++i){
        int o = obase + i;
        uvec2 u;
        u.x = pack2bf(vals[i][0], vals[i][1]);
        u.y = pack2bf(vals[i][2], vals[i][3]);
        *(uvec2*)(v_b + (b*256 + o)*NSP + n0) = u;
      }
    }
  }
}

// ---------------------------------------------------------------------------
// K6: flash attention, split-K=2, barrier-free. Per wave: 32 queries, 64-key
// tiles. S^T = mfma(A=K, B=Q^T, C=bias): D[key=lq*4+r][query=lc].
// P^T -> PV B-layout via per-wave LDS scratch of packed-bf16 key-pairs:
//   logical kp = key/2 (0..31), query = lc
//   physical dword = lc*32 + (kp ^ ((lc&7)<<2))   [xor keeps pairs/quads
//   contiguous+aligned; writes <=4-way banked, b128 reads bank-optimal]
// write: uvec2 (u0,u1) per g;  read: uvec4 -> short8 B-frag per mh.
// l = sum_keys P via ones-MFMA. Stores raw f32 O/l partials (K7 normalizes).
// grid (36 = 18 qblk x 2 split, 8 h, 4 b).
__global__ __launch_bounds__(256) void k6_attn(const unsigned short* __restrict__ q_t,
    const unsigned short* __restrict__ k_t, const unsigned short* __restrict__ v_b,
    const float* __restrict__ bias_a,
    float* __restrict__ o0, float* __restrict__ o1,
    float* __restrict__ l0, float* __restrict__ l1){
  int bx = blockIdx.x, h = blockIdx.y, b = blockIdx.z;
  int qblk = bx >> 1, s = bx & 1;
  float* op = s ? o1 : o0;
  float* lp = s ? l1 : l0;
  int t = threadIdx.x, wv = t >> 6, lane = t & 63;
  int lq = lane >> 4, lc = lane & 15;
  int bh = b*8 + h;
  int nb0 = qblk*128 + wv*32;
  const f32x4 z4 = {0.f, 0.f, 0.f, 0.f};
  __shared__ float ps[4][512];        // per-wave P scratch (2 KB each)
  float* myps = ps[wv];
  int xm = (lc & 7) << 2;             // xor swizzle mask (dwords)
  int wbase = lc*32;                  // per-query row base (dwords)
  const uvec4 onesu = {0x3F803F80u, 0x3F803F80u, 0x3F803F80u, 0x3F803F80u};
  const short8 aOnes = __builtin_bit_cast(short8, onesu);
  short8 aQ[2];
  #pragma unroll
  for (int qf = 0; qf < 2; ++qf)
    aQ[qf] = *(const short8*)(q_t + ((size_t)(bh*NSP + nb0 + qf*16 + lc))*32 + lq*8);
  f32x4 O[2][2];
  f32x4 Ol[2];
  #pragma unroll
  for (int qf = 0; qf < 2; ++qf){
    Ol[qf] = z4;
    #pragma unroll
    for (int dh = 0; dh < 2; ++dh) O[qf][dh] = z4;
  }
  const float* brow = bias_a + b*NSP;
  int ms = s*1152;

  for (int it = 0; it < 18; ++it){
    int m0 = ms + it*64;
    short8 aK[4]; fvec4 c0[4]; short8 aV[2][2];
    #pragma unroll
    for (int g = 0; g < 4; ++g)
      aK[g] = *(const short8*)(k_t + ((size_t)(bh*NSP + m0 + g*16 + lc))*32 + lq*8);
    #pragma unroll
    for (int g = 0; g < 4; ++g)
      c0[g] = *(const fvec4*)(brow + m0 + g*16 + lq*4);
    #pragma unroll
    for (int dh = 0; dh < 2; ++dh)
      #pragma unroll
      for (int mh = 0; mh < 2; ++mh)
        aV[dh][mh] = *(const short8*)(v_b + ((size_t)(b*256 + h*32 + dh*16 + lc))*NSP + m0 + mh*32 + lq*8);
    #pragma unroll
    for (int qf = 0; qf < 2; ++qf){
      // S^T for 64 keys x 16 queries; exp2; pack bf16 pairs; stash in scratch
      #pragma unroll
      for (int g = 0; g < 4; ++g){
        f32x4 S = __builtin_amdgcn_mfma_f32_16x16x32_bf16(aK[g], aQ[qf], c0[g], 0, 0, 0);
        uvec2 w2;
        w2.x = pack2bf(__builtin_amdgcn_exp2f(S[0]), __builtin_amdgcn_exp2f(S[1]));
        w2.y = pack2bf(__builtin_amdgcn_exp2f(S[2]), __builtin_amdgcn_exp2f(S[3]));
        int kp = g*8 + lq*2;          // logical key-pair index of (S[0],S[1])
        *(uvec2*)&myps[wbase + (kp ^ xm)] = w2;
      }
      // PV: read B-frag (keys mh*32+lq*8..+7, query lc) as one b128
      #pragma unroll
      for (int mh = 0; mh < 2; ++mh){
        int rb = (mh*16 + lq*4) ^ xm;
        uvec4 up = *(const uvec4*)&myps[wbase + rb];
        short8 bP = __builtin_bit_cast(short8, up);
        Ol[qf] = __builtin_amdgcn_mfma_f32_16x16x32_bf16(aOnes, bP, Ol[qf], 0, 0, 0);
        #pragma unroll
        for (int dh = 0; dh < 2; ++dh)
          O[qf][dh] = __builtin_amdgcn_mfma_f32_16x16x32_bf16(aV[dh][mh], bP, O[qf][dh], 0, 0, 0);
      }
    }
  }
  // store raw partials (normalization deferred to K7)
  #pragma unroll
  for (int qf = 0; qf < 2; ++qf){
    int nidx = nb0 + qf*16 + lc;
    if (lq == 0) lp[b*NSP + nidx] = Ol[qf][0];
    #pragma unroll
    for (int dh = 0; dh < 2; ++dh)
      #pragma unroll
      for (int r = 0; r < 4; ++r)
        op[((size_t)(b*256 + h*32 + dh*16 + lq*4 + r))*NSP + nidx] = O[qf][dh][r];
  }
}

// ---------------------------------------------------------------------------
// K7: out = wproj @ ((o0+o1)/(l0+l1)) + bproj. Normalization applied in the
// epilogue (rl depends only on n). grid (36 nt, 4 ct, 4 b).
__global__ __launch_bounds__(256) void k7_proj(const float* __restrict__ o0,
    const float* __restrict__ o1, const float* __restrict__ l0p,
    const float* __restrict__ l1p, const float* __restrict__ wproj,
    const float* __restrict__ bproj, float* __restrict__ out){
  int nt = blockIdx.x, ct = blockIdx.y, b = blockIdx.z, t = threadIdx.x;
  int tc = t >> 4, tn = t & 15;
  __shared__ float xs[32][68];
  __shared__ float wsm[32][68];
  __shared__ float rls[64];
  if (t < 64) rls[t] = 1.0f / (l0p[b*NSP + nt*64 + t] + l1p[b*NSP + nt*64 + t]);
  float acc[4][4];
  #pragma unroll
  for (int i = 0; i < 4; ++i)
    #pragma unroll
    for (int j = 0; j < 4; ++j) acc[i][j] = 0.f;
  for (int kc = 0; kc < 8; ++kc){
    __syncthreads();
    #pragma unroll
    for (int p2 = 0; p2 < 2; ++p2){
      int idx = t + 256*p2, k = idx >> 4, c4 = idx & 15;
      size_t gi = ((size_t)(b*256 + kc*32 + k))*NSP + nt*64 + c4*4;
      fvec4 a = *(const fvec4*)(o0 + gi);
      fvec4 bb = *(const fvec4*)(o1 + gi);
      fvec4 sum = a + bb;
      *(fvec4*)&xs[k][c4*4] = sum;
    }
    #pragma unroll
    for (int p2 = 0; p2 < 2; ++p2){
      int idx = t + 256*p2, co = idx >> 3, c4 = idx & 7;
      fvec4 w4 = *(const fvec4*)(wproj + (ct*64 + co)*256 + kc*32 + c4*4);
      wsm[c4*4+0][co] = w4[0]; wsm[c4*4+1][co] = w4[1];
      wsm[c4*4+2][co] = w4[2]; wsm[c4*4+3][co] = w4[3];
    }
    __syncthreads();
    for (int k = 0; k < 32; ++k){
      fvec4 xv = *(fvec4*)&xs[k][tn*4];
      fvec4 w4 = *(fvec4*)&wsm[k][tc*4];
      #pragma unroll
      for (int i = 0; i < 4; ++i)
        #pragma unroll
        for (int j = 0; j < 4; ++j) acc[i][j] += w4[i]*xv[j];
    }
  }
  int n0 = nt*64 + tn*4;
  float rl4[4];
  #pragma unroll
  for (int j = 0; j < 4; ++j) rl4[j] = rls[tn*4 + j];
  #pragma unroll
  for (int i = 0; i < 4; ++i){
    int co = ct*64 + tc*4 + i;
    float bp = bproj[co];
    fvec4 v;
    #pragma unroll
    for (int j = 0; j < 4; ++j) v[j] = acc[i][j]*rl4[j] + bp;
    *(fvec4*)(out + (b*256 + co)*NSP + n0) = v;
  }
}

// ---------------------------------------------------------------------------
extern "C" void kernel_launch(void* const* d_in, const int* in_sizes, int n_in,
                              void* d_out, int out_size, void* d_ws, size_t ws_size,
                              hipStream_t stream) {
  const float* x     = (const float*)d_in[0];
  const float* rgb   = (const float*)d_in[1];
  const float* wq    = (const float*)d_in[2];
  const float* bq    = (const float*)d_in[3];
  const float* wk    = (const float*)d_in[4];
  const float* bk    = (const float*)d_in[5];
  const float* wv    = (const float*)d_in[6];
  const float* bv    = (const float*)d_in[7];
  const float* wproj = (const float*)d_in[8];
  const float* bproj = (const float*)d_in[9];
  const float* c1w   = (const float*)d_in[10];
  const float* c1b   = (const float*)d_in[11];
  const float* c2w   = (const float*)d_in[12];
  const float* c2b   = (const float*)d_in[13];
  const float* gq_w  = (const float*)d_in[14];
  const float* gq_b  = (const float*)d_in[15];
  const float* bqf_w = (const float*)d_in[16];
  const float* bqf_b = (const float*)d_in[17];
  const float* gk_w  = (const float*)d_in[18];
  const float* gk_b  = (const float*)d_in[19];
  const float* bkf_w = (const float*)d_in[20];
  const float* bkf_b = (const float*)d_in[21];
  const float* gv_w  = (const float*)d_in[22];
  const float* gv_b  = (const float*)d_in[23];
  const float* bvf_w = (const float*)d_in[24];
  const float* bvf_b = (const float*)d_in[25];
  const float* alphaP= (const float*)d_in[26];

  char* w = (char*)d_ws;
  float* luma_n = (float*)w;            w += 4*NSP*4;             // 36864
  float* bias_a = (float*)w;            w += 4*NSP*4;             // 36864
  float* hm_sum = (float*)w;            w += 512*4;               // 2048
  float* film   = (float*)w;            w += 6*4*256*4;           // 24576
  unsigned short* h1p = (unsigned short*)w; w += 4*2500*128*2;    // 2,560,000 (padded bf16)
  unsigned short* wtb = (unsigned short*)w; w += 9*128*128*2;     // 294,912
  unsigned short* q_t = (unsigned short*)w; w += 4*8*NSP*32*2;    // 4,718,592
  unsigned short* k_t = (unsigned short*)w; w += 4*8*NSP*32*2;    // 4,718,592
  unsigned short* v_b = (unsigned short*)w; w += 4*256*NSP*2;     // 4,718,592
  float* o_part0 = (float*)w;           w += (size_t)4*256*NSP*4; // 9,437,184
  float* o_part1 = (float*)w;           w += (size_t)4*256*NSP*4; // 9,437,184
  float* l_part0 = (float*)w;           w += 4*NSP*4;             // 36864
  float* l_part1 = (float*)w;           w += 4*NSP*4;             // 36864
  // total ~36.1 MB

  (void)hipMemsetAsync(h1p, 0, (size_t)4*2500*128*2, stream);  // zero pad ring
  k1_luma <<<4, 256, 0, stream>>>(rgb, alphaP, luma_n, bias_a, hm_sum);
  k2_conv1<<<dim3(9,4,4), 256, 0, stream>>>(luma_n, c1w, c1b, h1p);
  k2b_wt  <<<576, 256, 0, stream>>>(c2w, wtb);
  k3_conv2<<<dim3(48,2,4), 256, 0, stream>>>(h1p, wtb, c2b, hm_sum);
  k4_film <<<24, 256, 0, stream>>>(hm_sum, gq_w, gq_b, bqf_w, bqf_b,
                                   gk_w, gk_b, bkf_w, bkf_b,
                                   gv_w, gv_b, bvf_w, bvf_b, film);
  k5_qkv  <<<dim3(36,4,4), 256, 0, stream>>>(x, wq, wk, wv, bq, bk, bv, film,
                                             q_t, k_t, v_b);
  k6_attn <<<dim3(36,8,4), 256, 0, stream>>>(q_t, k_t, v_b, bias_a,
                                             o_part0, o_part1, l_part0, l_part1);
  k7_proj <<<dim3(36,4,4), 256, 0, stream>>>(o_part0, o_part1, l_part0, l_part1,
                                             wproj, bproj, (float*)d_out);
}

// Round 6
// 297.722 us; speedup vs baseline: 1.9168x; 1.1668x over previous
//
#include <hip/hip_runtime.h>

// ---------------------------------------------------------------------------
// LuminanceAwareMHSA: B=4, C=256, H=W=48 (N=2304), HEADS=8, DH=32, HID=128
// Round 6: k5/k7 converted from fp32-VALU GEMMs to bf16 MFMA GEMMs.
//   k0b  cast all weights to bf16 (wtb for conv2, wqkvb, wprojb)
//   k0xt transpose x -> xt[b][n][c] bf16 (B-fragment layout for k5)
//   K1   luma + min/max norm + pooled-invL bias (pre-scaled alpha*log2e)
//   K2   conv1 3x3 (1->128) + relu -> bf16 padded h1p
//   K3   conv2 via mfma + relu + column-sum -> hm_sum atomics
//   K4   FiLM params (6 small GEMVs)
//   K5   QKV via MFMA + FiLM epilogue -> bf16 q_t/k_t [B,H,N,32], v [B,256,N]
//   K6   flash attention (split-K=2, per-wave LDS, no barriers)
//        -> bf16 O partials in [B,N,256] (k7 B-frag layout), f32 l partials
//   K7   projection via MFMA; split-combine by accumulating both partial
//        buffers through the MFMA C chain; rl[n]+bproj in epilogue -> d_out
// ---------------------------------------------------------------------------

#define NSP 2304
#define WID 48

typedef __attribute__((ext_vector_type(4))) float  fvec4;
typedef __attribute__((ext_vector_type(2))) unsigned int uvec2;
typedef __attribute__((ext_vector_type(4))) unsigned int uvec4;
typedef __attribute__((ext_vector_type(8))) short  short8;   // 8 bf16 (4 VGPRs)
typedef __attribute__((ext_vector_type(4))) float  f32x4;    // MFMA C/D

__device__ inline unsigned short f2bf(float f){
  unsigned int u = __builtin_bit_cast(unsigned int, f);
  u += 0x7fffu + ((u >> 16) & 1u);           // RNE
  return (unsigned short)(u >> 16);
}
__device__ inline unsigned pack2bf(float a, float b){
#if __has_builtin(__builtin_amdgcn_cvt_pk_bf16_f32)
  typedef __attribute__((ext_vector_type(2))) __bf16 bf16x2;
  bf16x2 r = __builtin_amdgcn_cvt_pk_bf16_f32(a, b);
  return __builtin_bit_cast(unsigned, r);
#else
  return (unsigned)f2bf(a) | ((unsigned)f2bf(b) << 16);
#endif
}

// ---------------------------------------------------------------------------
// k0b: cast weights to bf16. idx ranges: [0,147456) wtb, [..,344064) wqkvb,
// [..,409600) wprojb. grid 1600 x 256.
__global__ void k0b_wcast(const float* __restrict__ c2w, const float* __restrict__ wq,
                          const float* __restrict__ wk, const float* __restrict__ wv_,
                          const float* __restrict__ wproj,
                          unsigned short* __restrict__ wtb,
                          unsigned short* __restrict__ wqkvb,
                          unsigned short* __restrict__ wprojb){
  int idx = blockIdx.x*256 + threadIdx.x;
  if (idx < 147456){
    int ic = idx & 127, rem = idx >> 7;
    int oc = rem & 127, tap = rem >> 7;
    wtb[idx] = f2bf(c2w[(oc*128 + ic)*9 + tap]);
  } else if (idx < 344064){
    int j = idx - 147456;
    int mat = j >> 16, oc_ = j & 65535;
    const float* src = (mat == 0) ? wq : (mat == 1) ? wk : wv_;
    wqkvb[j] = f2bf(src[oc_]);
  } else {
    int j = idx - 344064;
    wprojb[j] = f2bf(wproj[j]);
  }
}

// ---------------------------------------------------------------------------
// k0xt: xt[b][n][c] = bf16(x[b][c][n]). grid (36 nt, 4 cc, 4 b), 64n x 64c tile.
__global__ __launch_bounds__(256) void k0xt(const float* __restrict__ x,
                                            unsigned short* __restrict__ xt){
  int nt = blockIdx.x, cc = blockIdx.y, b = blockIdx.z, t = threadIdx.x;
  __shared__ unsigned short tb[64*72];
  int cl0 = t >> 4;           // 0..15
  int nl0 = (t & 15) * 4;     // 0..60
  #pragma unroll
  for (int ps = 0; ps < 4; ++ps){
    int cl = cl0 + ps*16;
    fvec4 v = *(const fvec4*)(x + ((size_t)(b*256 + cc*64 + cl))*NSP + nt*64 + nl0);
    #pragma unroll
    for (int i = 0; i < 4; ++i) tb[(nl0+i)*72 + cl] = f2bf(v[i]);
  }
  __syncthreads();
  int nl = t >> 2, cg = (t & 3) * 16;
  uvec4 u0 = *(const uvec4*)&tb[nl*72 + cg];
  uvec4 u1 = *(const uvec4*)&tb[nl*72 + cg + 8];
  unsigned short* dst = xt + ((size_t)(b*NSP + nt*64 + nl))*256 + cc*64 + cg;
  *(uvec4*)dst = u0;
  *(uvec4*)(dst + 8) = u1;
}

// ---------------------------------------------------------------------------
// K1: luma -> minmax-normalize; 3x3 zero-pad avg-pool of (1-luma); mean-center
//     and pre-multiply by alpha*log2e (k6 uses exp2). Also zero hm_sum.
__global__ void k1_luma(const float* __restrict__ rgb, const float* __restrict__ alphaP,
                        float* __restrict__ luma_n, float* __restrict__ bias_a,
                        float* __restrict__ hm_sum){
  int b = blockIdx.x, t = threadIdx.x;
  __shared__ float ly[NSP];
  __shared__ float ll[NSP];
  __shared__ float red[256];
  __shared__ float red2[256];
  const float* rp = rgb + b*3*NSP;
  float lmin = 1e30f, lmax = -1e30f;
  for (int i = t; i < NSP; i += 256){
    float y = 0.299f*rp[i] + 0.587f*rp[NSP+i] + 0.114f*rp[2*NSP+i];
    ly[i] = y; lmin = fminf(lmin, y); lmax = fmaxf(lmax, y);
  }
  red[t] = lmin; red2[t] = lmax;
  __syncthreads();
  for (int s = 128; s > 0; s >>= 1){
    if (t < s){ red[t] = fminf(red[t], red[t+s]); red2[t] = fmaxf(red2[t], red2[t+s]); }
    __syncthreads();
  }
  float mn = red[0], mx = red2[0];
  float inv = 1.0f / (mx - mn + 1e-6f);
  for (int i = t; i < NSP; i += 256){
    float v = (ly[i] - mn) * inv;
    ll[i] = v;
    luma_n[b*NSP + i] = v;
  }
  if (t < 128) hm_sum[b*128 + t] = 0.f;
  __syncthreads();
  float pr[9]; float psum = 0.f;
  #pragma unroll
  for (int ii = 0; ii < 9; ++ii){
    int n = t + 256*ii;
    int row = n / WID, col = n - row*WID;
    float s = 0.f;
    #pragma unroll
    for (int dy = -1; dy <= 1; ++dy)
      #pragma unroll
      for (int dx = -1; dx <= 1; ++dx){
        int r2 = row+dy, c2 = col+dx;
        if (r2 >= 0 && r2 < WID && c2 >= 0 && c2 < WID) s += 1.0f - ll[r2*WID + c2];
      }
    pr[ii] = s * (1.f/9.f);
    psum += pr[ii];
  }
  __syncthreads();
  red[t] = psum;
  __syncthreads();
  for (int s = 128; s > 0; s >>= 1){
    if (t < s) red[t] += red[t+s];
    __syncthreads();
  }
  float mean = red[0] * (1.f/(float)NSP);
  float alpha = alphaP[0] * 1.4426950408889634f;   // fold log2(e) for exp2
  #pragma unroll
  for (int ii = 0; ii < 9; ++ii){
    int n = t + 256*ii;
    bias_a[b*NSP + n] = alpha * (pr[ii] - mean);
  }
}

// ---------------------------------------------------------------------------
// K2: conv1 3x3, 1 -> 128 channels, relu -> bf16 padded h1p[b][50*50][128].
__global__ void k2_conv1(const float* __restrict__ luma_n, const float* __restrict__ c1w,
                         const float* __restrict__ c1b, unsigned short* __restrict__ h1p){
  int nt = blockIdx.x, ocg = blockIdx.y, b = blockIdx.z, t = threadIdx.x;
  __shared__ float wsm[32*9];
  __shared__ float bsm[32];
  for (int i = t; i < 288; i += 256) wsm[i] = c1w[ocg*288 + i];
  if (t < 32) bsm[t] = c1b[ocg*32 + t];
  __syncthreads();
  int n = nt*256 + t;
  int row = n / WID, col = n - row*WID;
  const float* lp = luma_n + b*NSP;
  float lv[9];
  int k = 0;
  #pragma unroll
  for (int dy = -1; dy <= 1; ++dy)
    #pragma unroll
    for (int dx = -1; dx <= 1; ++dx, ++k){
      int r2 = row+dy, c2 = col+dx;
      lv[k] = (r2 >= 0 && r2 < WID && c2 >= 0 && c2 < WID) ? lp[r2*WID + c2] : 0.f;
    }
  unsigned int packed[16];
  #pragma unroll
  for (int oc2 = 0; oc2 < 16; ++oc2){
    float a0 = bsm[oc2*2], a1 = bsm[oc2*2+1];
    #pragma unroll
    for (int q = 0; q < 9; ++q){
      a0 += wsm[(oc2*2)*9 + q] * lv[q];
      a1 += wsm[(oc2*2+1)*9 + q] * lv[q];
    }
    packed[oc2] = pack2bf(fmaxf(a0, 0.f), fmaxf(a1, 0.f));
  }
  unsigned short* dst = h1p + ((size_t)(b*2500 + (row+1)*50 + (col+1)))*128 + ocg*32;
  #pragma unroll
  for (int q4 = 0; q4 < 4; ++q4)
    *(uvec4*)(dst + q4*8) = *(uvec4*)&packed[q4*4];
}

// ---------------------------------------------------------------------------
// K3: conv2 128->128 as 9 shifted MFMA GEMMs + relu + column-sum -> hm_sum.
__global__ __launch_bounds__(256) void k3_conv2(const unsigned short* __restrict__ h1p,
    const unsigned short* __restrict__ wtb, const float* __restrict__ c2b,
    float* __restrict__ hm_sum){
  int row = blockIdx.x, mh = blockIdx.y, b = blockIdx.z;
  int t = threadIdx.x, wv = t >> 6, lane = t & 63;
  int lq = lane >> 4, lc = lane & 15;
  int ocb = mh*64 + wv*16;
  const f32x4 z4 = {0.f, 0.f, 0.f, 0.f};
  f32x4 C[3] = {z4, z4, z4};
  const unsigned short* hbase = h1p + (size_t)b*2500*128;
  #pragma unroll
  for (int tap = 0; tap < 9; ++tap){
    int dy = tap/3 - 1, dx = tap%3 - 1;
    const unsigned short* wrow = wtb + (tap*128 + ocb + lc)*128 + lq*8;
    const unsigned short* hrow = hbase + ((row+dy+1)*50 + (dx+1) + lc)*128 + lq*8;
    #pragma unroll
    for (int kc = 0; kc < 4; ++kc){
      short8 aW = *(const short8*)(wrow + kc*32);
      #pragma unroll
      for (int ntp = 0; ntp < 3; ++ntp){
        short8 bH = *(const short8*)(hrow + ntp*16*128 + kc*32);
        C[ntp] = __builtin_amdgcn_mfma_f32_16x16x32_bf16(aW, bH, C[ntp], 0, 0, 0);
      }
    }
  }
  float s[4];
  #pragma unroll
  for (int r = 0; r < 4; ++r){
    float bias = c2b[ocb + lq*4 + r];
    float v = 0.f;
    #pragma unroll
    for (int ntp = 0; ntp < 3; ++ntp) v += fmaxf(C[ntp][r] + bias, 0.f);
    v += __shfl_xor(v, 1, 64);
    v += __shfl_xor(v, 2, 64);
    v += __shfl_xor(v, 4, 64);
    v += __shfl_xor(v, 8, 64);
    s[r] = v;
  }
  if (lc == 0){
    #pragma unroll
    for (int r = 0; r < 4; ++r)
      atomicAdd(&hm_sum[b*128 + ocb + lq*4 + r], s[r]);
  }
}

// ---------------------------------------------------------------------------
// K4: FiLM params. film[(m6*4 + b)*256 + o]
__global__ void k4_film(const float* __restrict__ hm_sum,
  const float* w0, const float* b0, const float* w1, const float* b1,
  const float* w2, const float* b2, const float* w3, const float* b3,
  const float* w4, const float* b4, const float* w5, const float* b5,
  float* __restrict__ film){
  __shared__ float hs[128];
  int bb = blockIdx.x & 3, m6 = blockIdx.x >> 2, t = threadIdx.x;
  if (t < 128) hs[t] = hm_sum[bb*128 + t] * (1.f/(float)NSP);
  __syncthreads();
  const float* wm[6] = {w0,w1,w2,w3,w4,w5};
  const float* bm[6] = {b0,b1,b2,b3,b4,b5};
  const float* w = wm[m6];
  int o = t;
  float a = bm[m6][o];
  for (int h2 = 0; h2 < 128; ++h2) a += hs[h2] * w[o*128 + h2];
  film[blockIdx.x*256 + t] = a;
}

// ---------------------------------------------------------------------------
// K5: QKV via bf16 MFMA. t[o][n] = sum_c w[o][c] x[c][n]; A = w (m=o,k=c),
// B = xt[b][n][c] (k=c contiguous). grid (36 nt, 6 ot, 4 b); ot: p=ot>>1,
// om_base=(ot&1)*128; wave: 32 o x 64 n. FiLM epilogue; emits q_t/k_t
// [B,8,N,32] bf16 (SCALE*log2e in q), v_b [B,256,N] bf16.
__global__ __launch_bounds__(256) void k5_qkv(const unsigned short* __restrict__ xt,
    const unsigned short* __restrict__ wqkvb,
    const float* __restrict__ bq, const float* __restrict__ bk, const float* __restrict__ bv,
    const float* __restrict__ film,
    unsigned short* __restrict__ q_t, unsigned short* __restrict__ k_t,
    unsigned short* __restrict__ v_b){
  int nt = blockIdx.x, ot = blockIdx.y, b = blockIdx.z;
  int t = threadIdx.x, wv = t >> 6, lane = t & 63;
  int lq = lane >> 4, lc = lane & 15;
  int p = ot >> 1;
  int omb = (ot & 1)*128 + wv*32;
  const unsigned short* wb = wqkvb + p*65536;
  const f32x4 z4 = {0.f, 0.f, 0.f, 0.f};
  f32x4 acc[2][4];
  #pragma unroll
  for (int oh = 0; oh < 2; ++oh)
    #pragma unroll
    for (int nq = 0; nq < 4; ++nq) acc[oh][nq] = z4;
  for (int kc = 0; kc < 8; ++kc){
    short8 aW[2];
    #pragma unroll
    for (int oh = 0; oh < 2; ++oh)
      aW[oh] = *(const short8*)(wb + (omb + oh*16 + lc)*256 + kc*32 + lq*8);
    short8 bX[4];
    #pragma unroll
    for (int nq = 0; nq < 4; ++nq)
      bX[nq] = *(const short8*)(xt + ((size_t)(b*NSP + nt*64 + nq*16 + lc))*256 + kc*32 + lq*8);
    #pragma unroll
    for (int oh = 0; oh < 2; ++oh)
      #pragma unroll
      for (int nq = 0; nq < 4; ++nq)
        acc[oh][nq] = __builtin_amdgcn_mfma_f32_16x16x32_bf16(aW[oh], bX[nq], acc[oh][nq], 0, 0, 0);
  }
  const float* bvec = (p == 0) ? bq : (p == 1) ? bk : bv;
  int hq = omb >> 5;                       // head (uniform per wave), p<2 only
  unsigned short* qk = (p == 0) ? q_t : k_t;
  #pragma unroll
  for (int oh = 0; oh < 2; ++oh){
    fvec4 g4 = *(const fvec4*)(film + (2*p*4 + b)*256 + omb + oh*16 + lq*4);
    fvec4 t4 = *(const fvec4*)(film + ((2*p+1)*4 + b)*256 + omb + oh*16 + lq*4);
    fvec4 z4b = *(const fvec4*)(bvec + omb + oh*16 + lq*4);
    #pragma unroll
    for (int nq = 0; nq < 4; ++nq){
      int n = nt*64 + nq*16 + lc;
      float v0 = g4[0]*(acc[oh][nq][0] + z4b[0]) + t4[0];
      float v1 = g4[1]*(acc[oh][nq][1] + z4b[1]) + t4[1];
      float v2 = g4[2]*(acc[oh][nq][2] + z4b[2]) + t4[2];
      float v3 = g4[3]*(acc[oh][nq][3] + z4b[3]) + t4[3];
      if (p == 0){
        const float sc = 0.17677669529663687f * 1.4426950408889634f;  // SCALE*log2e
        v0 *= sc; v1 *= sc; v2 *= sc; v3 *= sc;
      }
      if (p < 2){
        uvec2 u;
        u.x = pack2bf(v0, v1);
        u.y = pack2bf(v2, v3);
        *(uvec2*)(qk + ((size_t)((b*8 + hq)*NSP + n))*32 + oh*16 + lq*4) = u;
      } else {
        int om = omb + oh*16 + lq*4;
        v_b[((size_t)(b*256 + om + 0))*NSP + n] = f2bf(v0);
        v_b[((size_t)(b*256 + om + 1))*NSP + n] = f2bf(v1);
        v_b[((size_t)(b*256 + om + 2))*NSP + n] = f2bf(v2);
        v_b[((size_t)(b*256 + om + 3))*NSP + n] = f2bf(v3);
      }
    }
  }
}

// ---------------------------------------------------------------------------
// K6: flash attention, split-K=2, barrier-free. Per wave: 32 queries, 64-key
// tiles. S^T = mfma(A=K, B=Q^T, C=bias): D[key=lq*4+r][query=lc].
// P^T -> PV B-layout via per-wave LDS scratch (xor-swizzled packed bf16).
// l = sum_keys P via ones-MFMA. Stores bf16 O partials in [B,N,256] layout
// (k7 B-frag layout) + f32 l partials. grid (36 = 18 qblk x 2 split, 8 h, 4 b).
__global__ __launch_bounds__(256) void k6_attn(const unsigned short* __restrict__ q_t,
    const unsigned short* __restrict__ k_t, const unsigned short* __restrict__ v_b,
    const float* __restrict__ bias_a,
    unsigned short* __restrict__ o0, unsigned short* __restrict__ o1,
    float* __restrict__ l0, float* __restrict__ l1){
  int bx = blockIdx.x, h = blockIdx.y, b = blockIdx.z;
  int qblk = bx >> 1, s = bx & 1;
  unsigned short* op = s ? o1 : o0;
  float* lp = s ? l1 : l0;
  int t = threadIdx.x, wv = t >> 6, lane = t & 63;
  int lq = lane >> 4, lc = lane & 15;
  int bh = b*8 + h;
  int nb0 = qblk*128 + wv*32;
  const f32x4 z4 = {0.f, 0.f, 0.f, 0.f};
  __shared__ float ps[4][512];        // per-wave P scratch (2 KB each)
  float* myps = ps[wv];
  int xm = (lc & 7) << 2;             // xor swizzle mask (dwords)
  int wbase = lc*32;                  // per-query row base (dwords)
  const uvec4 onesu = {0x3F803F80u, 0x3F803F80u, 0x3F803F80u, 0x3F803F80u};
  const short8 aOnes = __builtin_bit_cast(short8, onesu);
  short8 aQ[2];
  #pragma unroll
  for (int qf = 0; qf < 2; ++qf)
    aQ[qf] = *(const short8*)(q_t + ((size_t)(bh*NSP + nb0 + qf*16 + lc))*32 + lq*8);
  f32x4 O[2][2];
  f32x4 Ol[2];
  #pragma unroll
  for (int qf = 0; qf < 2; ++qf){
    Ol[qf] = z4;
    #pragma unroll
    for (int dh = 0; dh < 2; ++dh) O[qf][dh] = z4;
  }
  const float* brow = bias_a + b*NSP;
  int ms = s*1152;

  for (int it = 0; it < 18; ++it){
    int m0 = ms + it*64;
    short8 aK[4]; fvec4 c0[4]; short8 aV[2][2];
    #pragma unroll
    for (int g = 0; g < 4; ++g)
      aK[g] = *(const short8*)(k_t + ((size_t)(bh*NSP + m0 + g*16 + lc))*32 + lq*8);
    #pragma unroll
    for (int g = 0; g < 4; ++g)
      c0[g] = *(const fvec4*)(brow + m0 + g*16 + lq*4);
    #pragma unroll
    for (int dh = 0; dh < 2; ++dh)
      #pragma unroll
      for (int mh = 0; mh < 2; ++mh)
        aV[dh][mh] = *(const short8*)(v_b + ((size_t)(b*256 + h*32 + dh*16 + lc))*NSP + m0 + mh*32 + lq*8);
    #pragma unroll
    for (int qf = 0; qf < 2; ++qf){
      #pragma unroll
      for (int g = 0; g < 4; ++g){
        f32x4 S = __builtin_amdgcn_mfma_f32_16x16x32_bf16(aK[g], aQ[qf], c0[g], 0, 0, 0);
        uvec2 w2;
        w2.x = pack2bf(__builtin_amdgcn_exp2f(S[0]), __builtin_amdgcn_exp2f(S[1]));
        w2.y = pack2bf(__builtin_amdgcn_exp2f(S[2]), __builtin_amdgcn_exp2f(S[3]));
        int kp = g*8 + lq*2;
        *(uvec2*)&myps[wbase + (kp ^ xm)] = w2;
      }
      #pragma unroll
      for (int mh = 0; mh < 2; ++mh){
        int rb = (mh*16 + lq*4) ^ xm;
        uvec4 up = *(const uvec4*)&myps[wbase + rb];
        short8 bP = __builtin_bit_cast(short8, up);
        Ol[qf] = __builtin_amdgcn_mfma_f32_16x16x32_bf16(aOnes, bP, Ol[qf], 0, 0, 0);
        #pragma unroll
        for (int dh = 0; dh < 2; ++dh)
          O[qf][dh] = __builtin_amdgcn_mfma_f32_16x16x32_bf16(aV[dh][mh], bP, O[qf][dh], 0, 0, 0);
      }
    }
  }
  // store bf16 O partials [b][n][og] (og = h*32 + d), f32 l partials
  #pragma unroll
  for (int qf = 0; qf < 2; ++qf){
    int nidx = nb0 + qf*16 + lc;
    if (lq == 0) lp[b*NSP + nidx] = Ol[qf][0];
    #pragma unroll
    for (int dh = 0; dh < 2; ++dh){
      uvec2 u;
      u.x = pack2bf(O[qf][dh][0], O[qf][dh][1]);
      u.y = pack2bf(O[qf][dh][2], O[qf][dh][3]);
      *(uvec2*)(op + ((size_t)(b*NSP + nidx))*256 + h*32 + dh*16 + lq*4) = u;
    }
  }
}

// ---------------------------------------------------------------------------
// K7: out[c][n] = (sum_o wproj[c][o]*(a0+a1)[o][n]) * rl[n] + bproj[c].
// bf16 MFMA; a0/a1 combined by accumulating both through the MFMA C chain.
// grid (72 nt(32 n), 2 ct(128 c), 4 b); wave: 32 c x 32 n.
__global__ __launch_bounds__(256) void k7_proj(const unsigned short* __restrict__ a0,
    const unsigned short* __restrict__ a1, const float* __restrict__ l0p,
    const float* __restrict__ l1p, const unsigned short* __restrict__ wprojb,
    const float* __restrict__ bproj, float* __restrict__ out){
  int nt = blockIdx.x, ct = blockIdx.y, b = blockIdx.z;
  int t = threadIdx.x, wv = t >> 6, lane = t & 63;
  int lq = lane >> 4, lc = lane & 15;
  __shared__ float rls[32];
  if (t < 32) rls[t] = 1.0f / (l0p[b*NSP + nt*32 + t] + l1p[b*NSP + nt*32 + t]);
  __syncthreads();
  int cb = ct*128 + wv*32;
  const f32x4 z4 = {0.f, 0.f, 0.f, 0.f};
  f32x4 acc[2][2];
  #pragma unroll
  for (int ch = 0; ch < 2; ++ch)
    #pragma unroll
    for (int nq = 0; nq < 2; ++nq) acc[ch][nq] = z4;
  for (int kc = 0; kc < 8; ++kc){
    short8 aW[2];
    #pragma unroll
    for (int ch = 0; ch < 2; ++ch)
      aW[ch] = *(const short8*)(wprojb + (cb + ch*16 + lc)*256 + kc*32 + lq*8);
    #pragma unroll
    for (int src = 0; src < 2; ++src){
      const unsigned short* ap = src ? a1 : a0;
      short8 bA[2];
      #pragma unroll
      for (int nq = 0; nq < 2; ++nq)
        bA[nq] = *(const short8*)(ap + ((size_t)(b*NSP + nt*32 + nq*16 + lc))*256 + kc*32 + lq*8);
      #pragma unroll
      for (int ch = 0; ch < 2; ++ch)
        #pragma unroll
        for (int nq = 0; nq < 2; ++nq)
          acc[ch][nq] = __builtin_amdgcn_mfma_f32_16x16x32_bf16(aW[ch], bA[nq], acc[ch][nq], 0, 0, 0);
    }
  }
  #pragma unroll
  for (int ch = 0; ch < 2; ++ch){
    #pragma unroll
    for (int nq = 0; nq < 2; ++nq){
      int n = nt*32 + nq*16 + lc;
      float rl = rls[nq*16 + lc];
      #pragma unroll
      for (int r = 0; r < 4; ++r){
        int c = cb + ch*16 + lq*4 + r;
        out[((size_t)(b*256 + c))*NSP + n] = acc[ch][nq][r]*rl + bproj[c];
      }
    }
  }
}

// ---------------------------------------------------------------------------
extern "C" void kernel_launch(void* const* d_in, const int* in_sizes, int n_in,
                              void* d_out, int out_size, void* d_ws, size_t ws_size,
                              hipStream_t stream) {
  const float* x     = (const float*)d_in[0];
  const float* rgb   = (const float*)d_in[1];
  const float* wq    = (const float*)d_in[2];
  const float* bq    = (const float*)d_in[3];
  const float* wk    = (const float*)d_in[4];
  const float* bk    = (const float*)d_in[5];
  const float* wv    = (const float*)d_in[6];
  const float* bv    = (const float*)d_in[7];
  const float* wproj = (const float*)d_in[8];
  const float* bproj = (const float*)d_in[9];
  const float* c1w   = (const float*)d_in[10];
  const float* c1b   = (const float*)d_in[11];
  const float* c2w   = (const float*)d_in[12];
  const float* c2b   = (const float*)d_in[13];
  const float* gq_w  = (const float*)d_in[14];
  const float* gq_b  = (const float*)d_in[15];
  const float* bqf_w = (const float*)d_in[16];
  const float* bqf_b = (const float*)d_in[17];
  const float* gk_w  = (const float*)d_in[18];
  const float* gk_b  = (const float*)d_in[19];
  const float* bkf_w = (const float*)d_in[20];
  const float* bkf_b = (const float*)d_in[21];
  const float* gv_w  = (const float*)d_in[22];
  const float* gv_b  = (const float*)d_in[23];
  const float* bvf_w = (const float*)d_in[24];
  const float* bvf_b = (const float*)d_in[25];
  const float* alphaP= (const float*)d_in[26];

  char* w = (char*)d_ws;
  float* luma_n = (float*)w;            w += 4*NSP*4;             // 36864
  float* bias_a = (float*)w;            w += 4*NSP*4;             // 36864
  float* hm_sum = (float*)w;            w += 512*4;               // 2048
  float* film   = (float*)w;            w += 6*4*256*4;           // 24576
  unsigned short* h1p = (unsigned short*)w; w += 4*2500*128*2;    // 2,560,000 (padded bf16)
  unsigned short* wtb = (unsigned short*)w; w += 9*128*128*2;     // 294,912
  unsigned short* wqkvb = (unsigned short*)w; w += 3*256*256*2;   // 393,216
  unsigned short* wprojb = (unsigned short*)w; w += 256*256*2;    // 131,072
  unsigned short* xt  = (unsigned short*)w; w += (size_t)4*NSP*256*2; // 4,718,592
  unsigned short* q_t = (unsigned short*)w; w += (size_t)4*8*NSP*32*2; // 4,718,592
  unsigned short* k_t = (unsigned short*)w; w += (size_t)4*8*NSP*32*2; // 4,718,592
  unsigned short* v_b = (unsigned short*)w; w += (size_t)4*256*NSP*2;  // 4,718,592
  unsigned short* o_part0 = (unsigned short*)w; w += (size_t)4*NSP*256*2; // 4,718,592
  unsigned short* o_part1 = (unsigned short*)w; w += (size_t)4*NSP*256*2; // 4,718,592
  float* l_part0 = (float*)w;           w += 4*NSP*4;             // 36864
  float* l_part1 = (float*)w;           w += 4*NSP*4;             // 36864
  // total ~31.9 MB

  (void)hipMemsetAsync(h1p, 0, (size_t)4*2500*128*2, stream);  // zero pad ring
  k0b_wcast<<<1600, 256, 0, stream>>>(c2w, wq, wk, wv, wproj, wtb, wqkvb, wprojb);
  k0xt    <<<dim3(36,4,4), 256, 0, stream>>>(x, xt);
  k1_luma <<<4, 256, 0, stream>>>(rgb, alphaP, luma_n, bias_a, hm_sum);
  k2_conv1<<<dim3(9,4,4), 256, 0, stream>>>(luma_n, c1w, c1b, h1p);
  k3_conv2<<<dim3(48,2,4), 256, 0, stream>>>(h1p, wtb, c2b, hm_sum);
  k4_film <<<24, 256, 0, stream>>>(hm_sum, gq_w, gq_b, bqf_w, bqf_b,
                                   gk_w, gk_b, bkf_w, bkf_b,
                                   gv_w, gv_b, bvf_w, bvf_b, film);
  k5_qkv  <<<dim3(36,6,4), 256, 0, stream>>>(xt, wqkvb, bq, bk, bv, film,
                                             q_t, k_t, v_b);
  k6_attn <<<dim3(36,8,4), 256, 0, stream>>>(q_t, k_t, v_b, bias_a,
                                             o_part0, o_part1, l_part0, l_part1);
  k7_proj <<<dim3(72,2,4), 256, 0, stream>>>(o_part0, o_part1, l_part0, l_part1,
                                             wprojb, bproj, (float*)d_out);
}